// Round 8
// baseline (42560.538 us; speedup 1.0000x reference)
//
#include <hip/hip_runtime.h>

#define Hh 512
#define Bb 256
#define Tt 512
#define NPR 128
#define BH (Bb*Hh)
#define WN (4*Hh*Hh)
#define LDSB (131072 + 256)

typedef __attribute__((ext_vector_type(8))) short bf8;
typedef __attribute__((ext_vector_type(4))) float f4;

#define MF(A,B,C) C = __builtin_amdgcn_mfma_f32_16x16x32_bf16(A,B,C,0,0,0)
#define ALD(p)    __hip_atomic_load((p),  __ATOMIC_RELAXED, __HIP_MEMORY_SCOPE_AGENT)
#define AST(p,v)  __hip_atomic_store((p), (v), __ATOMIC_RELAXED, __HIP_MEMORY_SCOPE_AGENT)

__device__ __forceinline__ unsigned short f2bf(float x) {
  unsigned u = __float_as_uint(x);
  return (unsigned short)((u + 0x7FFFu + ((u >> 16) & 1u)) >> 16);
}
__device__ __forceinline__ float bf2f(unsigned short h) {
  return __uint_as_float((unsigned)h << 16);
}

struct KP {
  const float *x, *eb0, *eb1, *db0, *db1, *eWih0, *dWih0, *linW, *linb;
  const unsigned short *eWhh0h,*eWhh0l,*eWih1h,*eWih1l,*eWhh1h,*eWhh1l;
  const unsigned short *dWhh0h,*dWhh0l,*dWih1h,*dWih1l,*dWhh1h,*dWhh1l;
  unsigned short *h0h0,*h0h1,*h0l0,*h0l1,*h1h0,*h1h1,*h1l0,*h1l1;
  float *c0,*c1,*pred,*out;
  unsigned *bar;
};

// ---- fence-free grid barrier: all cross-block data moves via sc01 (agent-scope
// ---- relaxed atomics, cache-bypassing), so NO threadfence/wbl2/inv is needed.
// ---- Each wave drains its vmem (sc01 stores visible once acked) before arrival.
__device__ void gsync(unsigned* bar, unsigned rnd) {
  asm volatile("s_waitcnt vmcnt(0)" ::: "memory");
  __syncthreads();
  if (threadIdx.x == 0) {
    const int grp = blockIdx.x >> 4;
    const unsigned a = __hip_atomic_fetch_add(bar + grp*16, 1u, __ATOMIC_RELAXED, __HIP_MEMORY_SCOPE_AGENT);
    if (a == rnd*16u + 15u) {
      const unsigned r = __hip_atomic_fetch_add(bar + 256, 1u, __ATOMIC_RELAXED, __HIP_MEMORY_SCOPE_AGENT);
      if (r == rnd*16u + 15u)
        AST(bar + 272, rnd + 1u);
    }
    while (ALD(bar + 272) <= rnd)
      __builtin_amdgcn_s_sleep(2);
  }
  __syncthreads();
  asm volatile("" ::: "memory");
}

// ---- one-time weight staging into LDS (XOR-swizzled 16B slots) ----
__device__ void stageA_w(const unsigned short* Wh, const unsigned short* Wl, int j0, char* L) {
  const int t = threadIdx.x;
  const int r = t >> 2, q = t & 3;
  const int n = (r >> 4)*Hh + j0 + (r & 15);
  const unsigned short* gh = Wh + (size_t)n*Hh;
  const unsigned short* gl = Wl + (size_t)n*Hh;
  char* rowp = L + r*1024;
  #pragma unroll
  for (int u = 0; u < 16; ++u) {
    const int s = q*16 + u;
    const int so = (s ^ (r & 7)) * 16;
    *(uint4*)(rowp + so)         = *(const uint4*)(gh + s*8);
    *(uint4*)(rowp + 65536 + so) = *(const uint4*)(gl + s*8);
  }
  __syncthreads();
}
__device__ void stageB_w(const unsigned short* Wh, const unsigned short* Wl, int j0, char* slab) {
  const int t = threadIdx.x;
  const int r = t >> 3, q = t & 7;
  const int n = (r >> 3)*Hh + j0 + (r & 7);
  const unsigned short* gh = Wh + (size_t)n*Hh;
  const unsigned short* gl = Wl + (size_t)n*Hh;
  char* rowp = slab + r*1024;
  #pragma unroll
  for (int u = 0; u < 8; ++u) {
    const int s = q*8 + u;
    const int so = (s ^ (r & 7)) * 16;
    *(uint4*)(rowp + so)         = *(const uint4*)(gh + s*8);
    *(uint4*)(rowp + 32768 + so) = *(const uint4*)(gl + s*8);
  }
  __syncthreads();
}

// ---- role A cell step: 64 rows x (4 gates x 16 j); W in LDS, c private-cached,
// ---- h/pred via sc01 ----
__device__ __forceinline__ void stepA(const KP& kp, const char* L, float* sS,
    int m0, int j0, int jg,
    const unsigned short* Ah, const unsigned short* Al,
    const float* sW, const float* bias, float* cst,
    unsigned short* Ho, unsigned short* Lo,
    int smode, int sarg)
{
  const int tid = threadIdx.x;
  if (smode == 0) {
    if (tid < 64) sS[tid] = kp.x[(size_t)(m0 + tid)*Tt + sarg];
  } else {
    const int bl = tid >> 2, part = tid & 3;
    const int b = m0 + bl;
    float a = 0.f;
    #pragma unroll
    for (int u = 0; u < 16; ++u)
      a += ALD(&kp.pred[(part*16 + u)*Bb + b]);
    a += __shfl_xor(a, 1, 64);
    a += __shfl_xor(a, 2, 64);
    const float s = a + kp.linb[0];
    if (part == 0) {
      sS[bl] = s;
      if (jg == 0 && sarg >= 1) kp.out[(size_t)b*NPR + (sarg - 1)] = s;
    }
  }
  __syncthreads();

  const int wv = tid >> 6, lane = tid & 63;
  const int r15 = lane & 15, kg = lane >> 4;
  f4 acc[4];
  #pragma unroll
  for (int g = 0; g < 4; ++g) acc[g] = (f4){0.f,0.f,0.f,0.f};
  const unsigned* Au = (const unsigned*)Ah;
  const unsigned* Lu = (const unsigned*)Al;
  const size_t bu = (size_t)(m0 + wv*16 + r15)*256 + kg*4;
  const int swz = r15 & 7;

  #pragma unroll
  for (int half = 0; half < 2; ++half) {
    bf8 ahv[8], alv[8];
    #pragma unroll
    for (int q = 0; q < 8; ++q) {
      const size_t o = bu + (size_t)(half*8 + q)*16;
      union { unsigned u[4]; bf8 v; } th, tl;
      #pragma unroll
      for (int d = 0; d < 4; ++d) {
        th.u[d] = ALD(Au + o + d);
        tl.u[d] = ALD(Lu + o + d);
      }
      ahv[q] = th.v; alv[q] = tl.v;
    }
    #pragma unroll
    for (int q = 0; q < 8; ++q) {
      const int ks = half*8 + q;
      const int so = ((ks*4 + kg) ^ swz) * 16;
      #pragma unroll
      for (int g = 0; g < 4; ++g) {
        const int ro = (g*16 + r15)*1024 + so;
        const bf8 w_h = *(const bf8*)(L + ro);
        const bf8 w_l = *(const bf8*)(L + 65536 + ro);
        MF(ahv[q], w_h, acc[g]);
        MF(alv[q], w_h, acc[g]);
        MF(ahv[q], w_l, acc[g]);
      }
    }
  }

  const int j = j0 + r15;
  const float sw0 = sW[j], sw1 = sW[Hh+j], sw2 = sW[2*Hh+j], sw3 = sW[3*Hh+j];
  const float bi = bias[j], bfv = bias[Hh+j], bgv = bias[2*Hh+j], bo = bias[3*Hh+j];
  #pragma unroll
  for (int r = 0; r < 4; ++r) {
    const int bloc = wv*16 + kg*4 + r;
    const float sv = sS[bloc];
    const size_t idx = (size_t)(m0 + bloc)*Hh + j;
    const float gi = acc[0][r] + bi  + sv*sw0;
    const float gf = acc[1][r] + bfv + sv*sw1;
    const float gg = acc[2][r] + bgv + sv*sw2;
    const float go = acc[3][r] + bo  + sv*sw3;
    const float si = 1.f/(1.f + expf(-gi));
    const float sf = 1.f/(1.f + expf(-gf));
    const float so_ = 1.f/(1.f + expf(-go));
    const float c2 = sf * cst[idx] + si * tanhf(gg);
    const float h2 = so_ * tanhf(c2);
    cst[idx] = c2;
    const unsigned hh2 = f2bf(h2);
    const unsigned ll2 = f2bf(h2 - bf2f((unsigned short)hh2));
    const unsigned ph = (unsigned)__shfl_xor((int)hh2, 1, 64);
    const unsigned pl = (unsigned)__shfl_xor((int)ll2, 1, 64);
    if (!(r15 & 1)) {
      AST((unsigned*)Ho + (idx >> 1), hh2 | (ph << 16));
      AST((unsigned*)Lo + (idx >> 1), ll2 | (pl << 16));
    }
  }
}

// ---- role B cell step: 128 rows x (4 gates x 8 j), 2 GEMMs; W in LDS ----
__device__ __forceinline__ void stepB(const KP& kp, const char* L,
    int m0, int j0, int jg,
    const unsigned short* A1h, const unsigned short* A1l,   // h1 prev
    const unsigned short* A2h, const unsigned short* A2l,   // h0 current
    const float* bias, float* cst,
    unsigned short* Ho, unsigned short* Lo, int doPred)
{
  const int tid = threadIdx.x, wv = tid >> 6, lane = tid & 63;
  const int r15 = lane & 15, kg = lane >> 4;
  f4 acc[2][2];
  acc[0][0] = acc[0][1] = acc[1][0] = acc[1][1] = (f4){0.f,0.f,0.f,0.f};
  const int swz = r15 & 7;
  #pragma unroll
  for (int gm = 0; gm < 2; ++gm) {
    const unsigned* Au = (const unsigned*)(gm ? A1h : A2h);  // slab0=Wih1(x=h0), slab1=Whh1(h1)
    const unsigned* Lu = (const unsigned*)(gm ? A1l : A2l);
    const char* Wh = L + gm*65536;
    const char* Wl = Wh + 32768;
    #pragma unroll
    for (int mr = 0; mr < 2; ++mr) {
      const size_t bu = (size_t)(m0 + wv*32 + mr*16 + r15)*256 + kg*4;
      #pragma unroll
      for (int half = 0; half < 2; ++half) {
        bf8 ahv[8], alv[8];
        #pragma unroll
        for (int q = 0; q < 8; ++q) {
          const size_t o = bu + (size_t)(half*8 + q)*16;
          union { unsigned u[4]; bf8 v; } th, tl;
          #pragma unroll
          for (int d = 0; d < 4; ++d) {
            th.u[d] = ALD(Au + o + d);
            tl.u[d] = ALD(Lu + o + d);
          }
          ahv[q] = th.v; alv[q] = tl.v;
        }
        #pragma unroll
        for (int q = 0; q < 8; ++q) {
          const int ks = half*8 + q;
          const int so = ((ks*4 + kg) ^ swz) * 16;
          const bf8 w0h = *(const bf8*)(Wh + r15*1024 + so);
          const bf8 w1h = *(const bf8*)(Wh + (16 + r15)*1024 + so);
          const bf8 w0l = *(const bf8*)(Wl + r15*1024 + so);
          const bf8 w1l = *(const bf8*)(Wl + (16 + r15)*1024 + so);
          MF(ahv[q], w0h, acc[mr][0]); MF(alv[q], w0h, acc[mr][0]); MF(ahv[q], w0l, acc[mr][0]);
          MF(ahv[q], w1h, acc[mr][1]); MF(alv[q], w1h, acc[mr][1]); MF(ahv[q], w1l, acc[mr][1]);
        }
      }
    }
  }
  // lane^8 exchange: gather all 4 gates for my (b,j)
  float og[2][2][4];
  #pragma unroll
  for (int m = 0; m < 2; ++m)
    #pragma unroll
    for (int t = 0; t < 2; ++t)
      #pragma unroll
      for (int c = 0; c < 4; ++c)
        og[m][t][c] = __shfl_xor(acc[m][t][c], 8, 64);
  const int bit = r15 >> 3;
  float gv[4][4];
  #pragma unroll
  for (int g = 0; g < 4; ++g)
    #pragma unroll
    for (int c = 0; c < 4; ++c) {
      const float mine = bit ? acc[1][g>>1][c] : acc[0][g>>1][c];
      const float oth  = bit ? og[1][g>>1][c]  : og[0][g>>1][c];
      gv[g][c] = ((g & 1) == bit) ? mine : oth;
    }
  const int j = j0 + (r15 & 7);
  const float bi = bias[j], bfv = bias[Hh+j], bgv = bias[2*Hh+j], bo = bias[3*Hh+j];
  float hs[4];
  #pragma unroll
  for (int r = 0; r < 4; ++r) {
    const int bl = wv*32 + bit*16 + kg*4 + r;
    const size_t idx = (size_t)(m0 + bl)*Hh + j;
    const float gi = gv[0][r] + bi;
    const float gf = gv[1][r] + bfv;
    const float gg = gv[2][r] + bgv;
    const float go = gv[3][r] + bo;
    const float si = 1.f/(1.f + expf(-gi));
    const float sf = 1.f/(1.f + expf(-gf));
    const float so_ = 1.f/(1.f + expf(-go));
    const float c2 = sf * cst[idx] + si * tanhf(gg);
    const float h2 = so_ * tanhf(c2);
    cst[idx] = c2;
    const unsigned hh2 = f2bf(h2);
    const unsigned ll2 = f2bf(h2 - bf2f((unsigned short)hh2));
    const unsigned ph = (unsigned)__shfl_xor((int)hh2, 1, 64);
    const unsigned pl = (unsigned)__shfl_xor((int)ll2, 1, 64);
    if (!(r15 & 1)) {
      AST((unsigned*)Ho + (idx >> 1), hh2 | (ph << 16));
      AST((unsigned*)Lo + (idx >> 1), ll2 | (pl << 16));
    }
    hs[r] = h2;
  }
  if (doPred) {
    const float lw = kp.linW[j];
    #pragma unroll
    for (int r = 0; r < 4; ++r) {
      float p = hs[r] * lw;
      p += __shfl_xor(p, 1, 64);
      p += __shfl_xor(p, 2, 64);
      p += __shfl_xor(p, 4, 64);
      if ((r15 & 7) == 0)
        AST(&kp.pred[jg*Bb + (m0 + wv*32 + bit*16 + kg*4 + r)], p);
    }
  }
}

#define PH0(p) ((p) ? kp.h0h1 : kp.h0h0)
#define PL0(p) ((p) ? kp.h0l1 : kp.h0l0)
#define PH1(p) ((p) ? kp.h1h1 : kp.h1h0)
#define PL1(p) ((p) ? kp.h1l1 : kp.h1l0)

__global__ __launch_bounds__(256, 1) void lstm_persist(KP kp) {
  extern __shared__ char L[];
  float* sS = (float*)(L + 131072);
  const int blk = blockIdx.x;
  const bool roleA = blk < 128;
  int m0, j0, jg;
  if (roleA) { jg = blk >> 2; m0 = (blk & 3) * 64; j0 = jg * 16; }
  else { const int b2 = blk - 128; jg = b2 >> 1; m0 = (b2 & 1) * 128; j0 = jg * 8; }

  if (roleA) stageA_w(kp.eWhh0h, kp.eWhh0l, j0, L);
  else { stageB_w(kp.eWih1h, kp.eWih1l, j0, L); stageB_w(kp.eWhh1h, kp.eWhh1l, j0, L + 65536); }

  unsigned rnd = 0;

  // ---- encoder: stage s = L0(t=s) || L1(t=s-1) ----
  for (int s = 0; s <= Tt; ++s) {
    if (roleA) {
      if (s < Tt)
        stepA(kp, L, sS, m0, j0, jg, PH0(s&1), PL0(s&1), kp.eWih0, kp.eb0,
              kp.c0, PH0((s+1)&1), PL0((s+1)&1), 0, s);
    } else {
      if (s >= 1)
        stepB(kp, L, m0, j0, jg, PH1((s-1)&1), PL1((s-1)&1), PH0(s&1), PL0(s&1),
              kp.eb1, kp.c1, PH1(s&1), PL1(s&1), 0);
    }
    gsync(kp.bar, rnd++);
  }

  // ---- transition: restage decoder weights ----
  if (roleA) stageA_w(kp.dWhh0h, kp.dWhh0l, j0, L);
  else { stageB_w(kp.dWih1h, kp.dWih1l, j0, L); stageB_w(kp.dWhh1h, kp.dWhh1l, j0, L + 65536); }

  // ---- decoder: 128 steps, 2 sub-stages each ----
  for (int i = 0; i < NPR; ++i) {
    if (roleA) {
      if (i == 0)
        stepA(kp, L, sS, m0, j0, jg, PH0(0), PL0(0), kp.dWih0, kp.db0,
              kp.c0, PH0(1), PL0(1), 0, Tt - 1);
      else
        stepA(kp, L, sS, m0, j0, jg, PH0(i&1), PL0(i&1), kp.dWih0, kp.db0,
              kp.c0, PH0((i+1)&1), PL0((i+1)&1), 1, i);
    }
    gsync(kp.bar, rnd++);
    if (!roleA)
      stepB(kp, L, m0, j0, jg, PH1(i&1), PL1(i&1), PH0((i+1)&1), PL0((i+1)&1),
            kp.db1, kp.c1, PH1((i+1)&1), PL1((i+1)&1), 1);
    gsync(kp.bar, rnd++);
  }

  // ---- tail: out[:,127] ----
  if (roleA && jg == 0) {
    const int tid = threadIdx.x, bl = tid >> 2, part = tid & 3, b = m0 + bl;
    float a = 0.f;
    #pragma unroll
    for (int u = 0; u < 16; ++u) a += ALD(&kp.pred[(part*16 + u)*Bb + b]);
    a += __shfl_xor(a, 1, 64);
    a += __shfl_xor(a, 2, 64);
    if (part == 0) kp.out[(size_t)b*NPR + 127] = a + kp.linb[0];
  }
}

__global__ __launch_bounds__(256) void conv_w(const float* __restrict__ src,
                                              unsigned short* __restrict__ hi,
                                              unsigned short* __restrict__ lo) {
  const int i = (blockIdx.x * 256 + threadIdx.x) * 4;
  const float4 v = *(const float4*)(src + i);
  const unsigned short h0 = f2bf(v.x), h1 = f2bf(v.y), h2 = f2bf(v.z), h3 = f2bf(v.w);
  ushort4 hv; hv.x = h0; hv.y = h1; hv.z = h2; hv.w = h3;
  ushort4 lv;
  lv.x = f2bf(v.x - bf2f(h0)); lv.y = f2bf(v.y - bf2f(h1));
  lv.z = f2bf(v.z - bf2f(h2)); lv.w = f2bf(v.w - bf2f(h3));
  *(ushort4*)(hi + i) = hv;
  *(ushort4*)(lo + i) = lv;
}

extern "C" void kernel_launch(void* const* d_in, const int* in_sizes, int n_in,
                              void* d_out, int out_size, void* d_ws, size_t ws_size,
                              hipStream_t stream) {
  const float* x     = (const float*)d_in[0];
  const float* eWih0 = (const float*)d_in[1];
  const float* eWhh0 = (const float*)d_in[2];
  const float* eb0   = (const float*)d_in[3];
  const float* eWih1 = (const float*)d_in[4];
  const float* eWhh1 = (const float*)d_in[5];
  const float* eb1   = (const float*)d_in[6];
  const float* dWih0 = (const float*)d_in[7];
  const float* dWhh0 = (const float*)d_in[8];
  const float* db0   = (const float*)d_in[9];
  const float* dWih1 = (const float*)d_in[10];
  const float* dWhh1 = (const float*)d_in[11];
  const float* db1   = (const float*)d_in[12];
  const float* linW  = (const float*)d_in[13];
  const float* linb  = (const float*)d_in[14];
  float* out = (float*)d_out;

  unsigned short* wb = (unsigned short*)d_ws;
  unsigned short* W[12];
  for (int k = 0; k < 12; ++k) W[k] = wb + (size_t)k*WN;
  unsigned short* sb = wb + (size_t)12*WN;   // 8 h buffers
  float* cb   = (float*)(sb + (size_t)8*BH);
  float* c0   = cb;
  float* c1   = cb + BH;
  float* pred = cb + 2*(size_t)BH;           // 64*256 floats
  unsigned* bar = (unsigned*)(pred + 64*Bb);

  (void)hipMemsetAsync(sb + 0*(size_t)BH, 0, (size_t)BH*2, stream); // h0h[0]
  (void)hipMemsetAsync(sb + 2*(size_t)BH, 0, (size_t)BH*2, stream); // h0l[0]
  (void)hipMemsetAsync(sb + 4*(size_t)BH, 0, (size_t)BH*2, stream); // h1h[0]
  (void)hipMemsetAsync(sb + 6*(size_t)BH, 0, (size_t)BH*2, stream); // h1l[0]
  (void)hipMemsetAsync(c0, 0, (size_t)BH*4, stream);
  (void)hipMemsetAsync(c1, 0, (size_t)BH*4, stream);
  (void)hipMemsetAsync(bar, 0, 2048, stream);

  conv_w<<<1024, 256, 0, stream>>>(eWhh0, W[0], W[1]);
  conv_w<<<1024, 256, 0, stream>>>(eWih1, W[2], W[3]);
  conv_w<<<1024, 256, 0, stream>>>(eWhh1, W[4], W[5]);
  conv_w<<<1024, 256, 0, stream>>>(dWhh0, W[6], W[7]);
  conv_w<<<1024, 256, 0, stream>>>(dWih1, W[8], W[9]);
  conv_w<<<1024, 256, 0, stream>>>(dWhh1, W[10], W[11]);

  KP kp;
  kp.x = x; kp.eb0 = eb0; kp.eb1 = eb1; kp.db0 = db0; kp.db1 = db1;
  kp.eWih0 = eWih0; kp.dWih0 = dWih0; kp.linW = linW; kp.linb = linb;
  kp.eWhh0h = W[0]; kp.eWhh0l = W[1];
  kp.eWih1h = W[2]; kp.eWih1l = W[3];
  kp.eWhh1h = W[4]; kp.eWhh1l = W[5];
  kp.dWhh0h = W[6]; kp.dWhh0l = W[7];
  kp.dWih1h = W[8]; kp.dWih1l = W[9];
  kp.dWhh1h = W[10]; kp.dWhh1l = W[11];
  kp.h0h0 = sb + 0*(size_t)BH; kp.h0h1 = sb + 1*(size_t)BH;
  kp.h0l0 = sb + 2*(size_t)BH; kp.h0l1 = sb + 3*(size_t)BH;
  kp.h1h0 = sb + 4*(size_t)BH; kp.h1h1 = sb + 5*(size_t)BH;
  kp.h1l0 = sb + 6*(size_t)BH; kp.h1l1 = sb + 7*(size_t)BH;
  kp.c0 = c0; kp.c1 = c1; kp.pred = pred; kp.out = out; kp.bar = bar;

  (void)hipFuncSetAttribute((const void*)lstm_persist,
                            hipFuncAttributeMaxDynamicSharedMemorySize, LDSB);
  void* kargs[] = { (void*)&kp };
  hipError_t rc = hipLaunchCooperativeKernel((const void*)lstm_persist, dim3(256), dim3(256),
                                             kargs, LDSB, stream);
  if (rc != hipSuccess) {
    // fallback: plain launch — 128KB LDS forces 1 block/CU; 256 blocks on 256 CUs co-resident
    lstm_persist<<<dim3(256), dim3(256), LDSB, stream>>>(kp);
  }
  (void)in_sizes; (void)n_in; (void)out_size; (void)ws_size;
}

// Round 9
// 12034.480 us; speedup vs baseline: 3.5365x; 3.5365x over previous
//
#include <hip/hip_runtime.h>

#define Hh 512
#define Bb 256
#define Tt 512
#define NPR 128
#define BH (Bb*Hh)
#define WN (4*Hh*Hh)
#define LDSB (131072 + 256)

typedef __attribute__((ext_vector_type(8))) short bf8;
typedef __attribute__((ext_vector_type(4))) float f4;
typedef __attribute__((ext_vector_type(4))) unsigned u4;

#define MF(A,B,C) C = __builtin_amdgcn_mfma_f32_16x16x32_bf16(A,B,C,0,0,0)
#define ALD(p)    __hip_atomic_load((p),  __ATOMIC_RELAXED, __HIP_MEMORY_SCOPE_AGENT)
#define AST(p,v)  __hip_atomic_store((p), (v), __ATOMIC_RELAXED, __HIP_MEMORY_SCOPE_AGENT)

__device__ __forceinline__ void ld16(u4& d, const u4* p) {
  asm volatile("global_load_dwordx4 %0, %1, off sc0 sc1" : "=&v"(d) : "v"(p));
}
__device__ __forceinline__ void st16(u4* p, u4 d) {
  asm volatile("global_store_dwordx4 %0, %1, off sc0 sc1" :: "v"(p), "v"(d) : "memory");
}
__device__ __forceinline__ bf8 asbf8(u4 v) {
  union { u4 u; bf8 b; } c; c.u = v; return c.b;
}
#define VW16 { asm volatile("s_waitcnt vmcnt(16)" ::: "memory"); __builtin_amdgcn_sched_barrier(0); }
#define VW0  { asm volatile("s_waitcnt vmcnt(0)"  ::: "memory"); __builtin_amdgcn_sched_barrier(0); }

__device__ __forceinline__ unsigned short f2bf(float x) {
  unsigned u = __float_as_uint(x);
  return (unsigned short)((u + 0x7FFFu + ((u >> 16) & 1u)) >> 16);
}
__device__ __forceinline__ float bf2f(unsigned short h) {
  return __uint_as_float((unsigned)h << 16);
}

// 8 lanes (lane&7 = e) each hold one bf16; returns the 8 packed in element order.
__device__ __forceinline__ u4 pack8(unsigned short v, int lane) {
  unsigned x = v;
  unsigned p1 = (unsigned)__shfl_xor((int)x, 1, 64);
  unsigned u  = (lane & 1) ? ((p1 & 0xFFFFu) | (x << 16)) : ((x & 0xFFFFu) | (p1 << 16));
  unsigned p2 = (unsigned)__shfl_xor((int)u, 2, 64);
  unsigned d0 = (lane & 2) ? p2 : u;
  unsigned d1 = (lane & 2) ? u  : p2;
  unsigned q0 = (unsigned)__shfl_xor((int)d0, 4, 64);
  unsigned q1 = (unsigned)__shfl_xor((int)d1, 4, 64);
  u4 r;
  if (lane & 4) { r[0] = q0; r[1] = q1; r[2] = d0; r[3] = d1; }
  else          { r[0] = d0; r[1] = d1; r[2] = q0; r[3] = q1; }
  return r;
}

struct KP {
  const float *x, *eb0, *eb1, *db0, *db1, *eWih0, *dWih0, *linW, *linb;
  const unsigned short *eWhh0h,*eWhh0l,*eWih1h,*eWih1l,*eWhh1h,*eWhh1l;
  const unsigned short *dWhh0h,*dWhh0l,*dWih1h,*dWih1l,*dWhh1h,*dWhh1l;
  u4 *h0h0,*h0h1,*h0l0,*h0l1,*h1h0,*h1h1,*h1l0,*h1l1;   // hT[kc][b] 16B slots
  float *c0,*c1,*pred,*out;
  unsigned *bar;
};

// ---- grid barrier: relaxed monotone counters + TREE release (split spin lines) ----
__device__ void gsync(unsigned* bar, unsigned rnd) {
  asm volatile("s_waitcnt vmcnt(0)" ::: "memory");
  __syncthreads();
  if (threadIdx.x == 0) {
    const int grp = blockIdx.x >> 4;
    unsigned* garr  = bar + grp*32;        // arrival counter (own line per group)
    unsigned* gflag = bar + grp*32 + 16;   // group release flag
    unsigned* cctr  = bar + 512;
    unsigned* cflag = bar + 520;
    const unsigned a = __hip_atomic_fetch_add(garr, 1u, __ATOMIC_RELAXED, __HIP_MEMORY_SCOPE_AGENT);
    if (a == rnd*16u + 15u) {              // last in group
      const unsigned r = __hip_atomic_fetch_add(cctr, 1u, __ATOMIC_RELAXED, __HIP_MEMORY_SCOPE_AGENT);
      if (r == rnd*16u + 15u) AST(cflag, rnd + 1u);
      while (ALD(cflag) <= rnd) __builtin_amdgcn_s_sleep(2);
      AST(gflag, rnd + 1u);
    } else {
      while (ALD(gflag) <= rnd) __builtin_amdgcn_s_sleep(2);
    }
  }
  __syncthreads();
  asm volatile("" ::: "memory");
}

// ---- one-time weight staging into LDS (XOR-swizzled 16B slots) ----
__device__ void stageA_w(const unsigned short* Wh, const unsigned short* Wl, int j0, char* L) {
  const int t = threadIdx.x;
  const int r = t >> 2, q = t & 3;
  const int n = (r >> 4)*Hh + j0 + (r & 15);
  const unsigned short* gh = Wh + (size_t)n*Hh;
  const unsigned short* gl = Wl + (size_t)n*Hh;
  char* rowp = L + r*1024;
  #pragma unroll
  for (int u = 0; u < 16; ++u) {
    const int s = q*16 + u;
    const int so = (s ^ (r & 7)) * 16;
    *(uint4*)(rowp + so)         = *(const uint4*)(gh + s*8);
    *(uint4*)(rowp + 65536 + so) = *(const uint4*)(gl + s*8);
  }
  __syncthreads();
}
__device__ void stageB_w(const unsigned short* Wh, const unsigned short* Wl, int j0, char* slab) {
  const int t = threadIdx.x;
  const int r = t >> 3, q = t & 7;
  const int n = (r >> 3)*Hh + j0 + (r & 7);
  const unsigned short* gh = Wh + (size_t)n*Hh;
  const unsigned short* gl = Wl + (size_t)n*Hh;
  char* rowp = slab + r*1024;
  #pragma unroll
  for (int u = 0; u < 8; ++u) {
    const int s = q*8 + u;
    const int so = (s ^ (r & 7)) * 16;
    *(uint4*)(rowp + so)         = *(const uint4*)(gh + s*8);
    *(uint4*)(rowp + 32768 + so) = *(const uint4*)(gl + s*8);
  }
  __syncthreads();
}

// ---- role A cell: 64 rows x (4 gates x 16 j); W in LDS; h via coalesced sc01 ----
__device__ __forceinline__ void stepA(const KP& kp, const char* L, float* sS,
    int m0, int j0, int jg,
    const u4* Ah, const u4* Al,
    const float* sW, const float* bias, float* cst,
    u4* Ho, u4* Lo,
    int smode, int sarg)
{
  const int tid = threadIdx.x;
  if (smode == 0) {
    if (tid < 64) sS[tid] = kp.x[(size_t)(m0 + tid)*Tt + sarg];
  } else {
    const int bl = tid >> 2, part = tid & 3;
    const int b = m0 + bl;
    float a = 0.f;
    #pragma unroll
    for (int u = 0; u < 16; ++u)
      a += ALD(&kp.pred[(part*16 + u)*Bb + b]);
    a += __shfl_xor(a, 1, 64);
    a += __shfl_xor(a, 2, 64);
    const float s = a + kp.linb[0];
    if (part == 0) {
      sS[bl] = s;
      if (jg == 0 && sarg >= 1) kp.out[(size_t)b*NPR + (sarg - 1)] = s;
    }
  }
  __syncthreads();

  const int wv = tid >> 6, lane = tid & 63;
  const int r15 = lane & 15, kg = lane >> 4;
  const int bb = m0 + wv*16 + r15;
  const u4* pAh = Ah + kg*256 + bb;
  const u4* pAl = Al + kg*256 + bb;
  f4 acc[4];
  #pragma unroll
  for (int g = 0; g < 4; ++g) acc[g] = (f4){0.f,0.f,0.f,0.f};
  const int swz = r15 & 7;

  u4 vh[16], vl[16];
  #pragma unroll
  for (int q = 0; q < 16; ++q) {
    ld16(vh[q], pAh + q*1024);     // slot stride per ks window: 4*256
    ld16(vl[q], pAl + q*1024);
  }
  VW16;                             // first 8 ks (hi+lo) landed
  #pragma unroll
  for (int q = 0; q < 8; ++q) {
    const int so = ((q*4 + kg) ^ swz) * 16;
    const bf8 a_h = asbf8(vh[q]), a_l = asbf8(vl[q]);
    #pragma unroll
    for (int g = 0; g < 4; ++g) {
      const int ro = (g*16 + r15)*1024 + so;
      const bf8 w_h = *(const bf8*)(L + ro);
      const bf8 w_l = *(const bf8*)(L + 65536 + ro);
      MF(a_h, w_h, acc[g]); MF(a_l, w_h, acc[g]); MF(a_h, w_l, acc[g]);
    }
  }
  VW0;
  #pragma unroll
  for (int q = 8; q < 16; ++q) {
    const int so = ((q*4 + kg) ^ swz) * 16;
    const bf8 a_h = asbf8(vh[q]), a_l = asbf8(vl[q]);
    #pragma unroll
    for (int g = 0; g < 4; ++g) {
      const int ro = (g*16 + r15)*1024 + so;
      const bf8 w_h = *(const bf8*)(L + ro);
      const bf8 w_l = *(const bf8*)(L + 65536 + ro);
      MF(a_h, w_h, acc[g]); MF(a_l, w_h, acc[g]); MF(a_h, w_l, acc[g]);
    }
  }

  const int j = j0 + r15;
  const float sw0 = sW[j], sw1 = sW[Hh+j], sw2 = sW[2*Hh+j], sw3 = sW[3*Hh+j];
  const float bi = bias[j], bfv = bias[Hh+j], bgv = bias[2*Hh+j], bo = bias[3*Hh+j];
  const int kcA = jg*2 + (r15 >> 3);
  #pragma unroll
  for (int r = 0; r < 4; ++r) {
    const int bloc = wv*16 + kg*4 + r;
    const float sv = sS[bloc];
    const size_t idx = (size_t)(m0 + bloc)*Hh + j;
    const float gi = acc[0][r] + bi  + sv*sw0;
    const float gf = acc[1][r] + bfv + sv*sw1;
    const float gg = acc[2][r] + bgv + sv*sw2;
    const float go = acc[3][r] + bo  + sv*sw3;
    const float si = 1.f/(1.f + expf(-gi));
    const float sf = 1.f/(1.f + expf(-gf));
    const float so_ = 1.f/(1.f + expf(-go));
    const float c2 = sf * cst[idx] + si * tanhf(gg);
    const float h2 = so_ * tanhf(c2);
    cst[idx] = c2;
    const unsigned short hh2 = f2bf(h2);
    const unsigned short ll2 = f2bf(h2 - bf2f(hh2));
    const u4 ph = pack8(hh2, lane);
    const u4 pl = pack8(ll2, lane);
    const int slot = kcA*256 + (m0 + wv*16 + kg*4 + r);
    if ((r15 & 7) == 0) { st16(Ho + slot, ph); st16(Lo + slot, pl); }
  }
}

// ---- role B cell: 128 rows x (4 gates x 8 j), 2 GEMMs; W in LDS ----
__device__ __forceinline__ void stepB(const KP& kp, const char* L,
    int m0, int j0, int jg,
    const u4* A1h, const u4* A1l,    // h1 prev
    const u4* A2h, const u4* A2l,    // h0 current
    const float* bias, float* cst,
    u4* Ho, u4* Lo, int doPred)
{
  const int tid = threadIdx.x, wv = tid >> 6, lane = tid & 63;
  const int r15 = lane & 15, kg = lane >> 4;
  f4 acc[2][2];
  acc[0][0] = acc[0][1] = acc[1][0] = acc[1][1] = (f4){0.f,0.f,0.f,0.f};
  const int swz = r15 & 7;
  #pragma unroll
  for (int gm = 0; gm < 2; ++gm) {
    const u4* Ah = gm ? A1h : A2h;   // slab0 = Wih1 (x = h0), slab1 = Whh1 (h1)
    const u4* Al = gm ? A1l : A2l;
    const char* Wh = L + gm*65536;
    const char* Wl = Wh + 32768;
    #pragma unroll
    for (int mr = 0; mr < 2; ++mr) {
      const int bb = m0 + wv*32 + mr*16 + r15;
      const u4* pAh = Ah + kg*256 + bb;
      const u4* pAl = Al + kg*256 + bb;
      u4 vh[16], vl[16];
      #pragma unroll
      for (int q = 0; q < 16; ++q) {
        ld16(vh[q], pAh + q*1024);
        ld16(vl[q], pAl + q*1024);
      }
      VW16;
      #pragma unroll
      for (int q = 0; q < 8; ++q) {
        const int so = ((q*4 + kg) ^ swz) * 16;
        const bf8 a_h = asbf8(vh[q]), a_l = asbf8(vl[q]);
        const bf8 w0h = *(const bf8*)(Wh + r15*1024 + so);
        const bf8 w1h = *(const bf8*)(Wh + (16 + r15)*1024 + so);
        const bf8 w0l = *(const bf8*)(Wl + r15*1024 + so);
        const bf8 w1l = *(const bf8*)(Wl + (16 + r15)*1024 + so);
        MF(a_h, w0h, acc[mr][0]); MF(a_l, w0h, acc[mr][0]); MF(a_h, w0l, acc[mr][0]);
        MF(a_h, w1h, acc[mr][1]); MF(a_l, w1h, acc[mr][1]); MF(a_h, w1l, acc[mr][1]);
      }
      VW0;
      #pragma unroll
      for (int q = 8; q < 16; ++q) {
        const int so = ((q*4 + kg) ^ swz) * 16;
        const bf8 a_h = asbf8(vh[q]), a_l = asbf8(vl[q]);
        const bf8 w0h = *(const bf8*)(Wh + r15*1024 + so);
        const bf8 w1h = *(const bf8*)(Wh + (16 + r15)*1024 + so);
        const bf8 w0l = *(const bf8*)(Wl + r15*1024 + so);
        const bf8 w1l = *(const bf8*)(Wl + (16 + r15)*1024 + so);
        MF(a_h, w0h, acc[mr][0]); MF(a_l, w0h, acc[mr][0]); MF(a_h, w0l, acc[mr][0]);
        MF(a_h, w1h, acc[mr][1]); MF(a_l, w1h, acc[mr][1]); MF(a_h, w1l, acc[mr][1]);
      }
    }
  }
  // lane^8 exchange: gather all 4 gates for my (b,j)
  float og[2][2][4];
  #pragma unroll
  for (int m = 0; m < 2; ++m)
    #pragma unroll
    for (int t = 0; t < 2; ++t)
      #pragma unroll
      for (int c = 0; c < 4; ++c)
        og[m][t][c] = __shfl_xor(acc[m][t][c], 8, 64);
  const int bit = r15 >> 3;
  float gv[4][4];
  #pragma unroll
  for (int g = 0; g < 4; ++g)
    #pragma unroll
    for (int c = 0; c < 4; ++c) {
      const float mine = bit ? acc[1][g>>1][c] : acc[0][g>>1][c];
      const float oth  = bit ? og[1][g>>1][c]  : og[0][g>>1][c];
      gv[g][c] = ((g & 1) == bit) ? mine : oth;
    }
  const int j = j0 + (r15 & 7);
  const float bi = bias[j], bfv = bias[Hh+j], bgv = bias[2*Hh+j], bo = bias[3*Hh+j];
  float hs[4];
  #pragma unroll
  for (int r = 0; r < 4; ++r) {
    const int bl = wv*32 + bit*16 + kg*4 + r;
    const size_t idx = (size_t)(m0 + bl)*Hh + j;
    const float gi = gv[0][r] + bi;
    const float gf = gv[1][r] + bfv;
    const float gg = gv[2][r] + bgv;
    const float go = gv[3][r] + bo;
    const float si = 1.f/(1.f + expf(-gi));
    const float sf = 1.f/(1.f + expf(-gf));
    const float so_ = 1.f/(1.f + expf(-go));
    const float c2 = sf * cst[idx] + si * tanhf(gg);
    const float h2 = so_ * tanhf(c2);
    cst[idx] = c2;
    const unsigned short hh2 = f2bf(h2);
    const unsigned short ll2 = f2bf(h2 - bf2f(hh2));
    const u4 ph = pack8(hh2, lane);
    const u4 pl = pack8(ll2, lane);
    const int slot = jg*256 + (m0 + wv*32 + bit*16 + kg*4 + r);
    if ((r15 & 7) == 0) { st16(Ho + slot, ph); st16(Lo + slot, pl); }
    hs[r] = h2;
  }
  if (doPred) {
    const float lw = kp.linW[j];
    #pragma unroll
    for (int r = 0; r < 4; ++r) {
      float p = hs[r] * lw;
      p += __shfl_xor(p, 1, 64);
      p += __shfl_xor(p, 2, 64);
      p += __shfl_xor(p, 4, 64);
      if ((r15 & 7) == 0)
        AST(&kp.pred[jg*Bb + (m0 + wv*32 + bit*16 + kg*4 + r)], p);
    }
  }
}

#define PH0(p) ((p) ? kp.h0h1 : kp.h0h0)
#define PL0(p) ((p) ? kp.h0l1 : kp.h0l0)
#define PH1(p) ((p) ? kp.h1h1 : kp.h1h0)
#define PL1(p) ((p) ? kp.h1l1 : kp.h1l0)

__global__ __launch_bounds__(256, 1) void lstm_persist(KP kp) {
  extern __shared__ char L[];
  float* sS = (float*)(L + 131072);
  const int blk = blockIdx.x;
  const bool roleA = blk < 128;
  int m0, j0, jg;
  if (roleA) { jg = blk >> 2; m0 = (blk & 3) * 64; j0 = jg * 16; }
  else { const int b2 = blk - 128; jg = b2 >> 1; m0 = (b2 & 1) * 128; j0 = jg * 8; }

  if (roleA) stageA_w(kp.eWhh0h, kp.eWhh0l, j0, L);
  else { stageB_w(kp.eWih1h, kp.eWih1l, j0, L); stageB_w(kp.eWhh1h, kp.eWhh1l, j0, L + 65536); }

  unsigned rnd = 0;

  // ---- encoder: stage s = L0(t=s) || L1(t=s-1) ----
  for (int s = 0; s <= Tt; ++s) {
    if (roleA) {
      if (s < Tt)
        stepA(kp, L, sS, m0, j0, jg, PH0(s&1), PL0(s&1), kp.eWih0, kp.eb0,
              kp.c0, PH0((s+1)&1), PL0((s+1)&1), 0, s);
    } else {
      if (s >= 1)
        stepB(kp, L, m0, j0, jg, PH1((s-1)&1), PL1((s-1)&1), PH0(s&1), PL0(s&1),
              kp.eb1, kp.c1, PH1(s&1), PL1(s&1), 0);
    }
    gsync(kp.bar, rnd++);
  }

  // ---- transition: restage decoder weights ----
  if (roleA) stageA_w(kp.dWhh0h, kp.dWhh0l, j0, L);
  else { stageB_w(kp.dWih1h, kp.dWih1l, j0, L); stageB_w(kp.dWhh1h, kp.dWhh1l, j0, L + 65536); }

  // ---- decoder: 128 steps, 2 sub-stages each ----
  for (int i = 0; i < NPR; ++i) {
    if (roleA) {
      if (i == 0)
        stepA(kp, L, sS, m0, j0, jg, PH0(0), PL0(0), kp.dWih0, kp.db0,
              kp.c0, PH0(1), PL0(1), 0, Tt - 1);
      else
        stepA(kp, L, sS, m0, j0, jg, PH0(i&1), PL0(i&1), kp.dWih0, kp.db0,
              kp.c0, PH0((i+1)&1), PL0((i+1)&1), 1, i);
    }
    gsync(kp.bar, rnd++);
    if (!roleA)
      stepB(kp, L, m0, j0, jg, PH1(i&1), PL1(i&1), PH0((i+1)&1), PL0((i+1)&1),
            kp.db1, kp.c1, PH1((i+1)&1), PL1((i+1)&1), 1);
    gsync(kp.bar, rnd++);
  }

  // ---- tail: out[:,127] ----
  if (roleA && jg == 0) {
    const int tid = threadIdx.x, bl = tid >> 2, part = tid & 3, b = m0 + bl;
    float a = 0.f;
    #pragma unroll
    for (int u = 0; u < 16; ++u) a += ALD(&kp.pred[(part*16 + u)*Bb + b]);
    a += __shfl_xor(a, 1, 64);
    a += __shfl_xor(a, 2, 64);
    if (part == 0) kp.out[(size_t)b*NPR + 127] = a + kp.linb[0];
  }
}

__global__ __launch_bounds__(256) void conv_w(const float* __restrict__ src,
                                              unsigned short* __restrict__ hi,
                                              unsigned short* __restrict__ lo) {
  const int i = (blockIdx.x * 256 + threadIdx.x) * 4;
  const float4 v = *(const float4*)(src + i);
  const unsigned short h0 = f2bf(v.x), h1 = f2bf(v.y), h2 = f2bf(v.z), h3 = f2bf(v.w);
  ushort4 hv; hv.x = h0; hv.y = h1; hv.z = h2; hv.w = h3;
  ushort4 lv;
  lv.x = f2bf(v.x - bf2f(h0)); lv.y = f2bf(v.y - bf2f(h1));
  lv.z = f2bf(v.z - bf2f(h2)); lv.w = f2bf(v.w - bf2f(h3));
  *(ushort4*)(hi + i) = hv;
  *(ushort4*)(lo + i) = lv;
}

extern "C" void kernel_launch(void* const* d_in, const int* in_sizes, int n_in,
                              void* d_out, int out_size, void* d_ws, size_t ws_size,
                              hipStream_t stream) {
  const float* x     = (const float*)d_in[0];
  const float* eWih0 = (const float*)d_in[1];
  const float* eWhh0 = (const float*)d_in[2];
  const float* eb0   = (const float*)d_in[3];
  const float* eWih1 = (const float*)d_in[4];
  const float* eWhh1 = (const float*)d_in[5];
  const float* eb1   = (const float*)d_in[6];
  const float* dWih0 = (const float*)d_in[7];
  const float* dWhh0 = (const float*)d_in[8];
  const float* db0   = (const float*)d_in[9];
  const float* dWih1 = (const float*)d_in[10];
  const float* dWhh1 = (const float*)d_in[11];
  const float* db1   = (const float*)d_in[12];
  const float* linW  = (const float*)d_in[13];
  const float* linb  = (const float*)d_in[14];
  float* out = (float*)d_out;

  unsigned short* wb = (unsigned short*)d_ws;
  unsigned short* W[12];
  for (int k = 0; k < 12; ++k) W[k] = wb + (size_t)k*WN;
  unsigned short* sb = wb + (size_t)12*WN;   // 8 h buffers (hT layout, 256KB each)
  float* cb   = (float*)(sb + (size_t)8*BH);
  float* c0   = cb;
  float* c1   = cb + BH;
  float* pred = cb + 2*(size_t)BH;           // 64*256 floats
  unsigned* bar = (unsigned*)(pred + 64*Bb);

  (void)hipMemsetAsync(sb + 0*(size_t)BH, 0, (size_t)BH*2, stream); // h0h[0]
  (void)hipMemsetAsync(sb + 2*(size_t)BH, 0, (size_t)BH*2, stream); // h0l[0]
  (void)hipMemsetAsync(sb + 4*(size_t)BH, 0, (size_t)BH*2, stream); // h1h[0]
  (void)hipMemsetAsync(sb + 6*(size_t)BH, 0, (size_t)BH*2, stream); // h1l[0]
  (void)hipMemsetAsync(c0, 0, (size_t)BH*4, stream);
  (void)hipMemsetAsync(c1, 0, (size_t)BH*4, stream);
  (void)hipMemsetAsync(bar, 0, 4096, stream);

  conv_w<<<1024, 256, 0, stream>>>(eWhh0, W[0], W[1]);
  conv_w<<<1024, 256, 0, stream>>>(eWih1, W[2], W[3]);
  conv_w<<<1024, 256, 0, stream>>>(eWhh1, W[4], W[5]);
  conv_w<<<1024, 256, 0, stream>>>(dWhh0, W[6], W[7]);
  conv_w<<<1024, 256, 0, stream>>>(dWih1, W[8], W[9]);
  conv_w<<<1024, 256, 0, stream>>>(dWhh1, W[10], W[11]);

  KP kp;
  kp.x = x; kp.eb0 = eb0; kp.eb1 = eb1; kp.db0 = db0; kp.db1 = db1;
  kp.eWih0 = eWih0; kp.dWih0 = dWih0; kp.linW = linW; kp.linb = linb;
  kp.eWhh0h = W[0]; kp.eWhh0l = W[1];
  kp.eWih1h = W[2]; kp.eWih1l = W[3];
  kp.eWhh1h = W[4]; kp.eWhh1l = W[5];
  kp.dWhh0h = W[6]; kp.dWhh0l = W[7];
  kp.dWih1h = W[8]; kp.dWih1l = W[9];
  kp.dWhh1h = W[10]; kp.dWhh1l = W[11];
  kp.h0h0 = (u4*)(sb + 0*(size_t)BH); kp.h0h1 = (u4*)(sb + 1*(size_t)BH);
  kp.h0l0 = (u4*)(sb + 2*(size_t)BH); kp.h0l1 = (u4*)(sb + 3*(size_t)BH);
  kp.h1h0 = (u4*)(sb + 4*(size_t)BH); kp.h1h1 = (u4*)(sb + 5*(size_t)BH);
  kp.h1l0 = (u4*)(sb + 6*(size_t)BH); kp.h1l1 = (u4*)(sb + 7*(size_t)BH);
  kp.c0 = c0; kp.c1 = c1; kp.pred = pred; kp.out = out; kp.bar = bar;

  (void)hipFuncSetAttribute((const void*)lstm_persist,
                            hipFuncAttributeMaxDynamicSharedMemorySize, LDSB);
  void* kargs[] = { (void*)&kp };
  hipError_t rc = hipLaunchCooperativeKernel((const void*)lstm_persist, dim3(256), dim3(256),
                                             kargs, LDSB, stream);
  if (rc != hipSuccess) {
    lstm_persist<<<dim3(256), dim3(256), LDSB, stream>>>(kp);
  }
  (void)in_sizes; (void)n_in; (void)out_size; (void)ws_size;
}

// Round 10
// 10145.445 us; speedup vs baseline: 4.1950x; 1.1862x over previous
//
#include <hip/hip_runtime.h>

#define Hh 512
#define Bb 256
#define Tt 512
#define NPR 128
#define BH (Bb*Hh)
#define WN (4*Hh*Hh)
#define LDSB (131072 + 256)

typedef __attribute__((ext_vector_type(8))) short bf8;
typedef __attribute__((ext_vector_type(4))) float f4;
typedef __attribute__((ext_vector_type(4))) unsigned u4;

#define MF(A,B,C) C = __builtin_amdgcn_mfma_f32_16x16x32_bf16(A,B,C,0,0,0)
#define ALD(p)    __hip_atomic_load((p),  __ATOMIC_RELAXED, __HIP_MEMORY_SCOPE_AGENT)
#define AST(p,v)  __hip_atomic_store((p), (v), __ATOMIC_RELAXED, __HIP_MEMORY_SCOPE_AGENT)

__device__ __forceinline__ void ld16(u4& d, const u4* p) {
  asm volatile("global_load_dwordx4 %0, %1, off sc0 sc1" : "=&v"(d) : "v"(p));
}
__device__ __forceinline__ void st16(u4* p, u4 d) {
  asm volatile("global_store_dwordx4 %0, %1, off sc0 sc1" :: "v"(p), "v"(d) : "memory");
}
__device__ __forceinline__ bf8 asbf8(u4 v) {
  union { u4 u; bf8 b; } c; c.u = v; return c.b;
}
#define VW16 { asm volatile("s_waitcnt vmcnt(16)" ::: "memory"); __builtin_amdgcn_sched_barrier(0); }
#define VW0  { asm volatile("s_waitcnt vmcnt(0)"  ::: "memory"); __builtin_amdgcn_sched_barrier(0); }

__device__ __forceinline__ unsigned short f2bf(float x) {
  unsigned u = __float_as_uint(x);
  return (unsigned short)((u + 0x7FFFu + ((u >> 16) & 1u)) >> 16);
}
__device__ __forceinline__ float bf2f(unsigned short h) {
  return __uint_as_float((unsigned)h << 16);
}

// fast gate math: native exp + rcp (errors ~1e-6 rel, far below numerics budget)
__device__ __forceinline__ float sigm(float x) {
  return __builtin_amdgcn_rcpf(1.f + __expf(-x));
}
__device__ __forceinline__ float tanh_f(float x) {
  x = fminf(15.f, fmaxf(-15.f, x));
  const float e = __expf(2.f * x);
  return (e - 1.f) * __builtin_amdgcn_rcpf(e + 1.f);
}

// 8 lanes (lane&7 = e) each hold one bf16; returns the 8 packed in element order.
__device__ __forceinline__ u4 pack8(unsigned short v, int lane) {
  unsigned x = v;
  unsigned p1 = (unsigned)__shfl_xor((int)x, 1, 64);
  unsigned u  = (lane & 1) ? ((p1 & 0xFFFFu) | (x << 16)) : ((x & 0xFFFFu) | (p1 << 16));
  unsigned p2 = (unsigned)__shfl_xor((int)u, 2, 64);
  unsigned d0 = (lane & 2) ? p2 : u;
  unsigned d1 = (lane & 2) ? u  : p2;
  unsigned q0 = (unsigned)__shfl_xor((int)d0, 4, 64);
  unsigned q1 = (unsigned)__shfl_xor((int)d1, 4, 64);
  u4 r;
  if (lane & 4) { r[0] = q0; r[1] = q1; r[2] = d0; r[3] = d1; }
  else          { r[0] = d0; r[1] = d1; r[2] = q0; r[3] = q1; }
  return r;
}

struct KP {
  const float *x, *eb0, *eb1, *db0, *db1, *eWih0, *dWih0, *linW, *linb;
  const unsigned short *eWhh0h,*eWhh0l,*eWih1h,*eWih1l,*eWhh1h,*eWhh1l;
  const unsigned short *dWhh0h,*dWhh0l,*dWih1h,*dWih1l,*dWhh1h,*dWhh1l;
  u4 *h0h0,*h0h1,*h0l0,*h0l1,*h1h0,*h1h1,*h1l0,*h1l1;   // hT[kc][b] 16B slots
  float *c0,*c1,*pred,*out;
  unsigned *bar;
};

// ---- grid barrier: 2-level relaxed arrival, SINGLE central flag broadcast spin ----
__device__ void gsync(unsigned* bar, unsigned rnd) {
  asm volatile("s_waitcnt vmcnt(0)" ::: "memory");
  __syncthreads();
  if (threadIdx.x == 0) {
    const int grp = blockIdx.x >> 4;
    unsigned* garr  = bar + grp*32;        // per-group arrival line
    unsigned* cctr  = bar + 512;           // central counter line
    unsigned* cflag = bar + 576;           // central release flag (own line)
    const unsigned a = __hip_atomic_fetch_add(garr, 1u, __ATOMIC_RELAXED, __HIP_MEMORY_SCOPE_AGENT);
    if (a == rnd*16u + 15u) {
      const unsigned r = __hip_atomic_fetch_add(cctr, 1u, __ATOMIC_RELAXED, __HIP_MEMORY_SCOPE_AGENT);
      if (r == rnd*16u + 15u) AST(cflag, rnd + 1u);
    }
    while (ALD(cflag) <= rnd) __builtin_amdgcn_s_sleep(2);
  }
  __syncthreads();
  asm volatile("" ::: "memory");
}

// ---- one-time weight staging into LDS (XOR-swizzled 16B slots) ----
__device__ void stageA_w(const unsigned short* Wh, const unsigned short* Wl, int j0, char* L) {
  const int t = threadIdx.x;
  const int r = t >> 2, q = t & 3;
  const int n = (r >> 4)*Hh + j0 + (r & 15);
  const unsigned short* gh = Wh + (size_t)n*Hh;
  const unsigned short* gl = Wl + (size_t)n*Hh;
  char* rowp = L + r*1024;
  #pragma unroll
  for (int u = 0; u < 16; ++u) {
    const int s = q*16 + u;
    const int so = (s ^ (r & 7)) * 16;
    *(uint4*)(rowp + so)         = *(const uint4*)(gh + s*8);
    *(uint4*)(rowp + 65536 + so) = *(const uint4*)(gl + s*8);
  }
  __syncthreads();
}
__device__ void stageB_w(const unsigned short* Wh, const unsigned short* Wl, int j0, char* slab) {
  const int t = threadIdx.x;
  const int r = t >> 3, q = t & 7;
  const int n = (r >> 3)*Hh + j0 + (r & 7);
  const unsigned short* gh = Wh + (size_t)n*Hh;
  const unsigned short* gl = Wl + (size_t)n*Hh;
  char* rowp = slab + r*1024;
  #pragma unroll
  for (int u = 0; u < 8; ++u) {
    const int s = q*8 + u;
    const int so = (s ^ (r & 7)) * 16;
    *(uint4*)(rowp + so)         = *(const uint4*)(gh + s*8);
    *(uint4*)(rowp + 32768 + so) = *(const uint4*)(gl + s*8);
  }
  __syncthreads();
}

// ---- role A cell: 64 rows x (4 gates x 16 j); W in LDS; h via coalesced sc01 ----
__device__ __forceinline__ void stepA(const KP& kp, const char* L, float* sS,
    int m0, int j0, int jg,
    const u4* Ah, const u4* Al,
    const float* sW, const float* bias, float* cst,
    u4* Ho, u4* Lo,
    int smode, int sarg)
{
  const int tid = threadIdx.x;
  if (smode == 0) {
    if (tid < 64) sS[tid] = kp.x[(size_t)(m0 + tid)*Tt + sarg];
  } else {
    const int bl = tid >> 2, part = tid & 3;
    const int b = m0 + bl;
    float a = 0.f;
    #pragma unroll
    for (int u = 0; u < 16; ++u)
      a += ALD(&kp.pred[(part*16 + u)*Bb + b]);
    a += __shfl_xor(a, 1, 64);
    a += __shfl_xor(a, 2, 64);
    const float s = a + kp.linb[0];
    if (part == 0) {
      sS[bl] = s;
      if (jg == 0 && sarg >= 1) kp.out[(size_t)b*NPR + (sarg - 1)] = s;
    }
  }
  __syncthreads();

  const int wv = tid >> 6, lane = tid & 63;
  const int r15 = lane & 15, kg = lane >> 4;
  const int bb = m0 + wv*16 + r15;
  const u4* pAh = Ah + kg*256 + bb;
  const u4* pAl = Al + kg*256 + bb;
  f4 acc[4];
  #pragma unroll
  for (int g = 0; g < 4; ++g) acc[g] = (f4){0.f,0.f,0.f,0.f};
  const int swz = r15 & 7;

  u4 vh[16], vl[16];
  #pragma unroll
  for (int q = 0; q < 16; ++q) {
    ld16(vh[q], pAh + q*1024);
    ld16(vl[q], pAl + q*1024);
  }
  VW16;
  #pragma unroll
  for (int q = 0; q < 8; ++q) {
    const int so = ((q*4 + kg) ^ swz) * 16;
    const bf8 a_h = asbf8(vh[q]), a_l = asbf8(vl[q]);
    #pragma unroll
    for (int g = 0; g < 4; ++g) {
      const int ro = (g*16 + r15)*1024 + so;
      const bf8 w_h = *(const bf8*)(L + ro);
      const bf8 w_l = *(const bf8*)(L + 65536 + ro);
      MF(a_h, w_h, acc[g]); MF(a_l, w_h, acc[g]); MF(a_h, w_l, acc[g]);
    }
  }
  VW0;
  #pragma unroll
  for (int q = 8; q < 16; ++q) {
    const int so = ((q*4 + kg) ^ swz) * 16;
    const bf8 a_h = asbf8(vh[q]), a_l = asbf8(vl[q]);
    #pragma unroll
    for (int g = 0; g < 4; ++g) {
      const int ro = (g*16 + r15)*1024 + so;
      const bf8 w_h = *(const bf8*)(L + ro);
      const bf8 w_l = *(const bf8*)(L + 65536 + ro);
      MF(a_h, w_h, acc[g]); MF(a_l, w_h, acc[g]); MF(a_h, w_l, acc[g]);
    }
  }

  const int j = j0 + r15;
  const float sw0 = sW[j], sw1 = sW[Hh+j], sw2 = sW[2*Hh+j], sw3 = sW[3*Hh+j];
  const float bi = bias[j], bfv = bias[Hh+j], bgv = bias[2*Hh+j], bo = bias[3*Hh+j];
  const int kcA = jg*2 + (r15 >> 3);
  #pragma unroll
  for (int r = 0; r < 4; ++r) {
    const int bloc = wv*16 + kg*4 + r;
    const float sv = sS[bloc];
    const size_t idx = (size_t)(m0 + bloc)*Hh + j;
    const float gi = acc[0][r] + bi  + sv*sw0;
    const float gf = acc[1][r] + bfv + sv*sw1;
    const float gg = acc[2][r] + bgv + sv*sw2;
    const float go = acc[3][r] + bo  + sv*sw3;
    const float c2 = sigm(gf) * cst[idx] + sigm(gi) * tanh_f(gg);
    const float h2 = sigm(go) * tanh_f(c2);
    cst[idx] = c2;
    const unsigned short hh2 = f2bf(h2);
    const unsigned short ll2 = f2bf(h2 - bf2f(hh2));
    const u4 ph = pack8(hh2, lane);
    const u4 pl = pack8(ll2, lane);
    const int slot = kcA*256 + (m0 + wv*16 + kg*4 + r);
    if ((r15 & 7) == 0) { st16(Ho + slot, ph); st16(Lo + slot, pl); }
  }
}

// ---- role B single-GEMM accumulate: 128 rows x (4g x 8j), one A-tensor, one W slab ----
__device__ __forceinline__ void stepB_gemm(const char* Wslab,
    const u4* Ah, const u4* Al, int m0, f4 acc[2][2])
{
  const int tid = threadIdx.x, wv = tid >> 6, lane = tid & 63;
  const int r15 = lane & 15, kg = lane >> 4;
  const int swz = r15 & 7;
  const char* Wh = Wslab;
  const char* Wl = Wslab + 32768;
  #pragma unroll
  for (int mr = 0; mr < 2; ++mr) {
    const int bb = m0 + wv*32 + mr*16 + r15;
    const u4* pAh = Ah + kg*256 + bb;
    const u4* pAl = Al + kg*256 + bb;
    u4 vh[16], vl[16];
    #pragma unroll
    for (int q = 0; q < 16; ++q) {
      ld16(vh[q], pAh + q*1024);
      ld16(vl[q], pAl + q*1024);
    }
    VW16;
    #pragma unroll
    for (int q = 0; q < 8; ++q) {
      const int so = ((q*4 + kg) ^ swz) * 16;
      const bf8 a_h = asbf8(vh[q]), a_l = asbf8(vl[q]);
      const bf8 w0h = *(const bf8*)(Wh + r15*1024 + so);
      const bf8 w1h = *(const bf8*)(Wh + (16 + r15)*1024 + so);
      const bf8 w0l = *(const bf8*)(Wl + r15*1024 + so);
      const bf8 w1l = *(const bf8*)(Wl + (16 + r15)*1024 + so);
      MF(a_h, w0h, acc[mr][0]); MF(a_l, w0h, acc[mr][0]); MF(a_h, w0l, acc[mr][0]);
      MF(a_h, w1h, acc[mr][1]); MF(a_l, w1h, acc[mr][1]); MF(a_h, w1l, acc[mr][1]);
    }
    VW0;
    #pragma unroll
    for (int q = 8; q < 16; ++q) {
      const int so = ((q*4 + kg) ^ swz) * 16;
      const bf8 a_h = asbf8(vh[q]), a_l = asbf8(vl[q]);
      const bf8 w0h = *(const bf8*)(Wh + r15*1024 + so);
      const bf8 w1h = *(const bf8*)(Wh + (16 + r15)*1024 + so);
      const bf8 w0l = *(const bf8*)(Wl + r15*1024 + so);
      const bf8 w1l = *(const bf8*)(Wl + (16 + r15)*1024 + so);
      MF(a_h, w0h, acc[mr][0]); MF(a_l, w0h, acc[mr][0]); MF(a_h, w0l, acc[mr][0]);
      MF(a_h, w1h, acc[mr][1]); MF(a_l, w1h, acc[mr][1]); MF(a_h, w1l, acc[mr][1]);
    }
  }
}

// ---- role B epilogue: gate exchange + c/h update + stores (+ pred partials) ----
__device__ __forceinline__ void stepB_fin(const KP& kp, int m0, int j0, int jg,
    f4 acc[2][2], const float* bias, float* cst, u4* Ho, u4* Lo, int doPred)
{
  const int tid = threadIdx.x, wv = tid >> 6, lane = tid & 63;
  const int r15 = lane & 15, kg = lane >> 4;
  float og[2][2][4];
  #pragma unroll
  for (int m = 0; m < 2; ++m)
    #pragma unroll
    for (int t = 0; t < 2; ++t)
      #pragma unroll
      for (int c = 0; c < 4; ++c)
        og[m][t][c] = __shfl_xor(acc[m][t][c], 8, 64);
  const int bit = r15 >> 3;
  float gv[4][4];
  #pragma unroll
  for (int g = 0; g < 4; ++g)
    #pragma unroll
    for (int c = 0; c < 4; ++c) {
      const float mine = bit ? acc[1][g>>1][c] : acc[0][g>>1][c];
      const float oth  = bit ? og[1][g>>1][c]  : og[0][g>>1][c];
      gv[g][c] = ((g & 1) == bit) ? mine : oth;
    }
  const int j = j0 + (r15 & 7);
  const float bi = bias[j], bfv = bias[Hh+j], bgv = bias[2*Hh+j], bo = bias[3*Hh+j];
  float hs[4];
  #pragma unroll
  for (int r = 0; r < 4; ++r) {
    const int bl = wv*32 + bit*16 + kg*4 + r;
    const size_t idx = (size_t)(m0 + bl)*Hh + j;
    const float gi = gv[0][r] + bi;
    const float gf = gv[1][r] + bfv;
    const float gg = gv[2][r] + bgv;
    const float go = gv[3][r] + bo;
    const float c2 = sigm(gf) * cst[idx] + sigm(gi) * tanh_f(gg);
    const float h2 = sigm(go) * tanh_f(c2);
    cst[idx] = c2;
    const unsigned short hh2 = f2bf(h2);
    const unsigned short ll2 = f2bf(h2 - bf2f(hh2));
    const u4 ph = pack8(hh2, lane);
    const u4 pl = pack8(ll2, lane);
    const int slot = jg*256 + (m0 + wv*32 + bit*16 + kg*4 + r);
    if ((r15 & 7) == 0) { st16(Ho + slot, ph); st16(Lo + slot, pl); }
    hs[r] = h2;
  }
  if (doPred) {
    const float lw = kp.linW[j];
    #pragma unroll
    for (int r = 0; r < 4; ++r) {
      float p = hs[r] * lw;
      p += __shfl_xor(p, 1, 64);
      p += __shfl_xor(p, 2, 64);
      p += __shfl_xor(p, 4, 64);
      if ((r15 & 7) == 0)
        AST(&kp.pred[jg*Bb + (m0 + wv*32 + bit*16 + kg*4 + r)], p);
    }
  }
}

#define PH0(p) ((p) ? kp.h0h1 : kp.h0h0)
#define PL0(p) ((p) ? kp.h0l1 : kp.h0l0)
#define PH1(p) ((p) ? kp.h1h1 : kp.h1h0)
#define PL1(p) ((p) ? kp.h1l1 : kp.h1l0)

__global__ __launch_bounds__(256, 1) void lstm_persist(KP kp) {
  extern __shared__ char L[];
  float* sS = (float*)(L + 131072);
  const int blk = blockIdx.x;
  const bool roleA = blk < 128;
  int m0, j0, jg;
  if (roleA) { jg = blk >> 2; m0 = (blk & 3) * 64; j0 = jg * 16; }
  else { const int b2 = blk - 128; jg = b2 >> 1; m0 = (b2 & 1) * 128; j0 = jg * 8; }

  if (roleA) stageA_w(kp.eWhh0h, kp.eWhh0l, j0, L);
  else { stageB_w(kp.eWih1h, kp.eWih1l, j0, L); stageB_w(kp.eWhh1h, kp.eWhh1l, j0, L + 65536); }

  unsigned rnd = 0;

  // ---- encoder: stage s = L0(t=s) || L1(t=s-1) ----
  for (int s = 0; s <= Tt; ++s) {
    if (roleA) {
      if (s < Tt)
        stepA(kp, L, sS, m0, j0, jg, PH0(s&1), PL0(s&1), kp.eWih0, kp.eb0,
              kp.c0, PH0((s+1)&1), PL0((s+1)&1), 0, s);
    } else {
      if (s >= 1) {
        f4 acc[2][2];
        acc[0][0] = acc[0][1] = acc[1][0] = acc[1][1] = (f4){0.f,0.f,0.f,0.f};
        stepB_gemm(L,         PH0(s&1),     PL0(s&1),     m0, acc);  // h0(s) @ Wih1
        stepB_gemm(L + 65536, PH1((s-1)&1), PL1((s-1)&1), m0, acc);  // h1(s-1) @ Whh1
        stepB_fin(kp, m0, j0, jg, acc, kp.eb1, kp.c1, PH1(s&1), PL1(s&1), 0);
      }
    }
    gsync(kp.bar, rnd++);
  }

  // ---- transition: restage decoder weights ----
  if (roleA) stageA_w(kp.dWhh0h, kp.dWhh0l, j0, L);
  else { stageB_w(kp.dWih1h, kp.dWih1l, j0, L); stageB_w(kp.dWhh1h, kp.dWhh1l, j0, L + 65536); }

  // ---- decoder: 128 steps; role-B precomputes h1@Whh1 during cell0 phase ----
  for (int i = 0; i < NPR; ++i) {
    f4 acc[2][2];
    acc[0][0] = acc[0][1] = acc[1][0] = acc[1][1] = (f4){0.f,0.f,0.f,0.f};
    if (roleA) {
      if (i == 0)
        stepA(kp, L, sS, m0, j0, jg, PH0(0), PL0(0), kp.dWih0, kp.db0,
              kp.c0, PH0(1), PL0(1), 0, Tt - 1);
      else
        stepA(kp, L, sS, m0, j0, jg, PH0(i&1), PL0(i&1), kp.dWih0, kp.db0,
              kp.c0, PH0((i+1)&1), PL0((i+1)&1), 1, i);
    } else {
      stepB_gemm(L + 65536, PH1(i&1), PL1(i&1), m0, acc);            // h1(i) @ Whh1 (pre)
    }
    gsync(kp.bar, rnd++);
    if (!roleA) {
      stepB_gemm(L, PH0((i+1)&1), PL0((i+1)&1), m0, acc);            // h0(i+1) @ Wih1
      stepB_fin(kp, m0, j0, jg, acc, kp.db1, kp.c1, PH1((i+1)&1), PL1((i+1)&1), 1);
    }
    gsync(kp.bar, rnd++);
  }

  // ---- tail: out[:,127] ----
  if (roleA && jg == 0) {
    const int tid = threadIdx.x, bl = tid >> 2, part = tid & 3, b = m0 + bl;
    float a = 0.f;
    #pragma unroll
    for (int u = 0; u < 16; ++u) a += ALD(&kp.pred[(part*16 + u)*Bb + b]);
    a += __shfl_xor(a, 1, 64);
    a += __shfl_xor(a, 2, 64);
    if (part == 0) kp.out[(size_t)b*NPR + 127] = a + kp.linb[0];
  }
}

__global__ __launch_bounds__(256) void conv_w(const float* __restrict__ src,
                                              unsigned short* __restrict__ hi,
                                              unsigned short* __restrict__ lo) {
  const int i = (blockIdx.x * 256 + threadIdx.x) * 4;
  const float4 v = *(const float4*)(src + i);
  const unsigned short h0 = f2bf(v.x), h1 = f2bf(v.y), h2 = f2bf(v.z), h3 = f2bf(v.w);
  ushort4 hv; hv.x = h0; hv.y = h1; hv.z = h2; hv.w = h3;
  ushort4 lv;
  lv.x = f2bf(v.x - bf2f(h0)); lv.y = f2bf(v.y - bf2f(h1));
  lv.z = f2bf(v.z - bf2f(h2)); lv.w = f2bf(v.w - bf2f(h3));
  *(ushort4*)(hi + i) = hv;
  *(ushort4*)(lo + i) = lv;
}

extern "C" void kernel_launch(void* const* d_in, const int* in_sizes, int n_in,
                              void* d_out, int out_size, void* d_ws, size_t ws_size,
                              hipStream_t stream) {
  const float* x     = (const float*)d_in[0];
  const float* eWih0 = (const float*)d_in[1];
  const float* eWhh0 = (const float*)d_in[2];
  const float* eb0   = (const float*)d_in[3];
  const float* eWih1 = (const float*)d_in[4];
  const float* eWhh1 = (const float*)d_in[5];
  const float* eb1   = (const float*)d_in[6];
  const float* dWih0 = (const float*)d_in[7];
  const float* dWhh0 = (const float*)d_in[8];
  const float* db0   = (const float*)d_in[9];
  const float* dWih1 = (const float*)d_in[10];
  const float* dWhh1 = (const float*)d_in[11];
  const float* db1   = (const float*)d_in[12];
  const float* linW  = (const float*)d_in[13];
  const float* linb  = (const float*)d_in[14];
  float* out = (float*)d_out;

  unsigned short* wb = (unsigned short*)d_ws;
  unsigned short* W[12];
  for (int k = 0; k < 12; ++k) W[k] = wb + (size_t)k*WN;
  unsigned short* sb = wb + (size_t)12*WN;   // 8 h buffers (hT layout)
  float* cb   = (float*)(sb + (size_t)8*BH);
  float* c0   = cb;
  float* c1   = cb + BH;
  float* pred = cb + 2*(size_t)BH;           // 64*256 floats
  unsigned* bar = (unsigned*)(pred + 64*Bb);

  (void)hipMemsetAsync(sb + 0*(size_t)BH, 0, (size_t)BH*2, stream); // h0h[0]
  (void)hipMemsetAsync(sb + 2*(size_t)BH, 0, (size_t)BH*2, stream); // h0l[0]
  (void)hipMemsetAsync(sb + 4*(size_t)BH, 0, (size_t)BH*2, stream); // h1h[0]
  (void)hipMemsetAsync(sb + 6*(size_t)BH, 0, (size_t)BH*2, stream); // h1l[0]
  (void)hipMemsetAsync(c0, 0, (size_t)BH*4, stream);
  (void)hipMemsetAsync(c1, 0, (size_t)BH*4, stream);
  (void)hipMemsetAsync(bar, 0, 4096, stream);

  conv_w<<<1024, 256, 0, stream>>>(eWhh0, W[0], W[1]);
  conv_w<<<1024, 256, 0, stream>>>(eWih1, W[2], W[3]);
  conv_w<<<1024, 256, 0, stream>>>(eWhh1, W[4], W[5]);
  conv_w<<<1024, 256, 0, stream>>>(dWhh0, W[6], W[7]);
  conv_w<<<1024, 256, 0, stream>>>(dWih1, W[8], W[9]);
  conv_w<<<1024, 256, 0, stream>>>(dWhh1, W[10], W[11]);

  KP kp;
  kp.x = x; kp.eb0 = eb0; kp.eb1 = eb1; kp.db0 = db0; kp.db1 = db1;
  kp.eWih0 = eWih0; kp.dWih0 = dWih0; kp.linW = linW; kp.linb = linb;
  kp.eWhh0h = W[0]; kp.eWhh0l = W[1];
  kp.eWih1h = W[2]; kp.eWih1l = W[3];
  kp.eWhh1h = W[4]; kp.eWhh1l = W[5];
  kp.dWhh0h = W[6]; kp.dWhh0l = W[7];
  kp.dWih1h = W[8]; kp.dWih1l = W[9];
  kp.dWhh1h = W[10]; kp.dWhh1l = W[11];
  kp.h0h0 = (u4*)(sb + 0*(size_t)BH); kp.h0h1 = (u4*)(sb + 1*(size_t)BH);
  kp.h0l0 = (u4*)(sb + 2*(size_t)BH); kp.h0l1 = (u4*)(sb + 3*(size_t)BH);
  kp.h1h0 = (u4*)(sb + 4*(size_t)BH); kp.h1h1 = (u4*)(sb + 5*(size_t)BH);
  kp.h1l0 = (u4*)(sb + 6*(size_t)BH); kp.h1l1 = (u4*)(sb + 7*(size_t)BH);
  kp.c0 = c0; kp.c1 = c1; kp.pred = pred; kp.out = out; kp.bar = bar;

  (void)hipFuncSetAttribute((const void*)lstm_persist,
                            hipFuncAttributeMaxDynamicSharedMemorySize, LDSB);
  void* kargs[] = { (void*)&kp };
  hipError_t rc = hipLaunchCooperativeKernel((const void*)lstm_persist, dim3(256), dim3(256),
                                             kargs, LDSB, stream);
  if (rc != hipSuccess) {
    lstm_persist<<<dim3(256), dim3(256), LDSB, stream>>>(kp);
  }
  (void)in_sizes; (void)n_in; (void)out_size; (void)ws_size;
}

// Round 11
// 9454.371 us; speedup vs baseline: 4.5017x; 1.0731x over previous
//
#include <hip/hip_runtime.h>

#define Hh 512
#define Bb 256
#define Tt 512
#define NPR 128
#define BH (Bb*Hh)
#define WN (4*Hh*Hh)
#define LDSB (131072 + 256)

typedef __attribute__((ext_vector_type(8))) short bf8;
typedef __attribute__((ext_vector_type(4))) float f4;
typedef __attribute__((ext_vector_type(4))) unsigned u4;

#define MF(A,B,C) C = __builtin_amdgcn_mfma_f32_16x16x32_bf16(A,B,C,0,0,0)
#define ALD(p)    __hip_atomic_load((p),  __ATOMIC_RELAXED, __HIP_MEMORY_SCOPE_AGENT)
#define AST(p,v)  __hip_atomic_store((p), (v), __ATOMIC_RELAXED, __HIP_MEMORY_SCOPE_AGENT)

__device__ __forceinline__ void ld16(u4& d, const u4* p) {
  asm volatile("global_load_dwordx4 %0, %1, off sc0 sc1" : "=&v"(d) : "v"(p));
}
__device__ __forceinline__ void st16(u4* p, u4 d) {
  asm volatile("global_store_dwordx4 %0, %1, off sc0 sc1" :: "v"(p), "v"(d) : "memory");
}
__device__ __forceinline__ bf8 asbf8(u4 v) {
  union { u4 u; bf8 b; } c; c.u = v; return c.b;
}
#define VW16 { asm volatile("s_waitcnt vmcnt(16)" ::: "memory"); __builtin_amdgcn_sched_barrier(0); }
#define VW0  { asm volatile("s_waitcnt vmcnt(0)"  ::: "memory"); __builtin_amdgcn_sched_barrier(0); }

__device__ __forceinline__ unsigned short f2bf(float x) {
  unsigned u = __float_as_uint(x);
  return (unsigned short)((u + 0x7FFFu + ((u >> 16) & 1u)) >> 16);
}
__device__ __forceinline__ float bf2f(unsigned short h) {
  return __uint_as_float((unsigned)h << 16);
}

__device__ __forceinline__ float sigm(float x) {
  return __builtin_amdgcn_rcpf(1.f + __expf(-x));
}
__device__ __forceinline__ float tanh_f(float x) {
  x = fminf(15.f, fmaxf(-15.f, x));
  const float e = __expf(2.f * x);
  return (e - 1.f) * __builtin_amdgcn_rcpf(e + 1.f);
}

// 8 lanes (lane&7 = e) each hold one bf16; returns the 8 packed in element order.
__device__ __forceinline__ u4 pack8(unsigned short v, int lane) {
  unsigned x = v;
  unsigned p1 = (unsigned)__shfl_xor((int)x, 1, 64);
  unsigned u  = (lane & 1) ? ((p1 & 0xFFFFu) | (x << 16)) : ((x & 0xFFFFu) | (p1 << 16));
  unsigned p2 = (unsigned)__shfl_xor((int)u, 2, 64);
  unsigned d0 = (lane & 2) ? p2 : u;
  unsigned d1 = (lane & 2) ? u  : p2;
  unsigned q0 = (unsigned)__shfl_xor((int)d0, 4, 64);
  unsigned q1 = (unsigned)__shfl_xor((int)d1, 4, 64);
  u4 r;
  if (lane & 4) { r[0] = q0; r[1] = q1; r[2] = d0; r[3] = d1; }
  else          { r[0] = d0; r[1] = d1; r[2] = q0; r[3] = q1; }
  return r;
}

struct KP {
  const float *x, *eb0, *eb1, *db0, *db1, *eWih0, *dWih0, *linW, *linb;
  const unsigned short *eWhh0h,*eWhh0l,*eWih1h,*eWih1l,*eWhh1h,*eWhh1l;
  const unsigned short *dWhh0h,*dWhh0l,*dWih1h,*dWih1l,*dWhh1h,*dWhh1l;
  u4 *h0h0,*h0h1,*h0l0,*h0l1,*h1h0,*h1h1,*h1l0,*h1l1;   // hT[kc][b] 16B slots
  float *c0,*c1,*pred,*out;
  unsigned *bar;
};

// ---- flat grid barrier: single arrival counter + single release flag (relaxed) ----
__device__ void gsync(unsigned* bar, unsigned rnd) {
  asm volatile("s_waitcnt vmcnt(0)" ::: "memory");
  __syncthreads();
  if (threadIdx.x == 0) {
    unsigned* ctr  = bar;          // own line
    unsigned* flag = bar + 64;     // own line
    const unsigned a = __hip_atomic_fetch_add(ctr, 1u, __ATOMIC_RELAXED, __HIP_MEMORY_SCOPE_AGENT);
    if (a == rnd*256u + 255u) AST(flag, rnd + 1u);
    while (ALD(flag) <= rnd) __builtin_amdgcn_s_sleep(1);
  }
  __syncthreads();
  asm volatile("" ::: "memory");
}

// ---- one-time weight staging into LDS (XOR-swizzled 16B slots), 512 threads ----
__device__ void stageA_w(const unsigned short* Wh, const unsigned short* Wl, int j0, char* L) {
  const int t = threadIdx.x;
  const int r = t >> 3, q = t & 7;          // 64 rows x 8 chunks
  const int n = (r >> 4)*Hh + j0 + (r & 15);
  const unsigned short* gh = Wh + (size_t)n*Hh;
  const unsigned short* gl = Wl + (size_t)n*Hh;
  char* rowp = L + r*1024;
  #pragma unroll
  for (int u = 0; u < 8; ++u) {
    const int s = q*8 + u;
    const int so = (s ^ (r & 7)) * 16;
    *(uint4*)(rowp + so)         = *(const uint4*)(gh + s*8);
    *(uint4*)(rowp + 65536 + so) = *(const uint4*)(gl + s*8);
  }
  __syncthreads();
}
__device__ void stageB_w(const unsigned short* Wh, const unsigned short* Wl, int j0, char* slab) {
  const int t = threadIdx.x;
  const int r = t >> 4, q = t & 15;         // 32 rows x 16 chunks
  const int n = (r >> 3)*Hh + j0 + (r & 7);
  const unsigned short* gh = Wh + (size_t)n*Hh;
  const unsigned short* gl = Wl + (size_t)n*Hh;
  char* rowp = slab + r*1024;
  #pragma unroll
  for (int u = 0; u < 4; ++u) {
    const int s = q*4 + u;
    const int so = (s ^ (r & 7)) * 16;
    *(uint4*)(rowp + so)         = *(const uint4*)(gh + s*8);
    *(uint4*)(rowp + 32768 + so) = *(const uint4*)(gl + s*8);
  }
  __syncthreads();
}

// ---- role A cell: 64 rows x (4 gates x 16 j); waves 0-3 compute, 4-7 assist sync ----
__device__ __forceinline__ void stepA(const KP& kp, const char* L, float* sS,
    int m0, int j0, int jg,
    const u4* Ah, const u4* Al,
    const float* sW, const float* bias, float* cst,
    u4* Ho, u4* Lo, int smode, int sarg)
{
  const int tid = threadIdx.x;
  if (smode == 0) {
    if (tid < 64) sS[tid] = kp.x[(size_t)(m0 + tid)*Tt + sarg];
  } else if (tid < 256) {
    const int bl = tid >> 2, part = tid & 3;
    const int b = m0 + bl;
    float a = 0.f;
    #pragma unroll
    for (int u = 0; u < 16; ++u)
      a += ALD(&kp.pred[(part*16 + u)*Bb + b]);
    a += __shfl_xor(a, 1, 64);
    a += __shfl_xor(a, 2, 64);
    const float s = a + kp.linb[0];
    if (part == 0) {
      sS[bl] = s;
      if (jg == 0 && sarg >= 1) kp.out[(size_t)b*NPR + (sarg - 1)] = s;
    }
  }
  __syncthreads();

  const int wv = tid >> 6;
  if (wv >= 4) return;                      // no further block syncs below
  const int lane = tid & 63;
  const int r15 = lane & 15, kg = lane >> 4;
  const int bb = m0 + wv*16 + r15;
  const u4* pAh = Ah + kg*256 + bb;
  const u4* pAl = Al + kg*256 + bb;
  f4 acc[4];
  #pragma unroll
  for (int g = 0; g < 4; ++g) acc[g] = (f4){0.f,0.f,0.f,0.f};
  const int swz = r15 & 7;

  u4 vh[16], vl[16];
  #pragma unroll
  for (int q = 0; q < 16; ++q) {
    ld16(vh[q], pAh + q*1024);
    ld16(vl[q], pAl + q*1024);
  }
  VW16;
  #pragma unroll
  for (int q = 0; q < 8; ++q) {
    const int so = ((q*4 + kg) ^ swz) * 16;
    const bf8 a_h = asbf8(vh[q]), a_l = asbf8(vl[q]);
    #pragma unroll
    for (int g = 0; g < 4; ++g) {
      const int ro = (g*16 + r15)*1024 + so;
      const bf8 w_h = *(const bf8*)(L + ro);
      const bf8 w_l = *(const bf8*)(L + 65536 + ro);
      MF(a_h, w_h, acc[g]); MF(a_l, w_h, acc[g]); MF(a_h, w_l, acc[g]);
    }
  }
  VW0;
  #pragma unroll
  for (int q = 8; q < 16; ++q) {
    const int so = ((q*4 + kg) ^ swz) * 16;
    const bf8 a_h = asbf8(vh[q]), a_l = asbf8(vl[q]);
    #pragma unroll
    for (int g = 0; g < 4; ++g) {
      const int ro = (g*16 + r15)*1024 + so;
      const bf8 w_h = *(const bf8*)(L + ro);
      const bf8 w_l = *(const bf8*)(L + 65536 + ro);
      MF(a_h, w_h, acc[g]); MF(a_l, w_h, acc[g]); MF(a_h, w_l, acc[g]);
    }
  }

  const int j = j0 + r15;
  const float sw0 = sW[j], sw1 = sW[Hh+j], sw2 = sW[2*Hh+j], sw3 = sW[3*Hh+j];
  const float bi = bias[j], bfv = bias[Hh+j], bgv = bias[2*Hh+j], bo = bias[3*Hh+j];
  const int kcA = jg*2 + (r15 >> 3);
  #pragma unroll
  for (int r = 0; r < 4; ++r) {
    const int bloc = wv*16 + kg*4 + r;
    const float sv = sS[bloc];
    const size_t idx = (size_t)(m0 + bloc)*Hh + j;
    const float gi = acc[0][r] + bi  + sv*sw0;
    const float gf = acc[1][r] + bfv + sv*sw1;
    const float gg = acc[2][r] + bgv + sv*sw2;
    const float go = acc[3][r] + bo  + sv*sw3;
    const float c2 = sigm(gf) * cst[idx] + sigm(gi) * tanh_f(gg);
    const float h2 = sigm(go) * tanh_f(c2);
    cst[idx] = c2;
    const unsigned short hh2 = f2bf(h2);
    const unsigned short ll2 = f2bf(h2 - bf2f(hh2));
    const u4 ph = pack8(hh2, lane);
    const u4 pl = pack8(ll2, lane);
    const int slot = kcA*256 + (m0 + wv*16 + kg*4 + r);
    if ((r15 & 7) == 0) { st16(Ho + slot, ph); st16(Lo + slot, pl); }
  }
}

// ---- role B GEMM: 8 waves x 16 rows, one A tensor-pair vs one W slab ----
__device__ __forceinline__ void stepB_gemm(const char* Wslab,
    const u4* Ah, const u4* Al, int m0, f4* acc)
{
  const int tid = threadIdx.x, wv = tid >> 6, lane = tid & 63;
  const int r15 = lane & 15, kg = lane >> 4;
  const int swz = r15 & 7;
  const char* Wh = Wslab;
  const char* Wl = Wslab + 32768;
  const int bb = m0 + wv*16 + r15;
  const u4* pAh = Ah + kg*256 + bb;
  const u4* pAl = Al + kg*256 + bb;
  u4 vh[16], vl[16];
  #pragma unroll
  for (int q = 0; q < 16; ++q) {
    ld16(vh[q], pAh + q*1024);
    ld16(vl[q], pAl + q*1024);
  }
  VW16;
  #pragma unroll
  for (int q = 0; q < 8; ++q) {
    const int so = ((q*4 + kg) ^ swz) * 16;
    const bf8 a_h = asbf8(vh[q]), a_l = asbf8(vl[q]);
    const bf8 w0h = *(const bf8*)(Wh + r15*1024 + so);
    const bf8 w1h = *(const bf8*)(Wh + (16 + r15)*1024 + so);
    const bf8 w0l = *(const bf8*)(Wl + r15*1024 + so);
    const bf8 w1l = *(const bf8*)(Wl + (16 + r15)*1024 + so);
    MF(a_h, w0h, acc[0]); MF(a_l, w0h, acc[0]); MF(a_h, w0l, acc[0]);
    MF(a_h, w1h, acc[1]); MF(a_l, w1h, acc[1]); MF(a_h, w1l, acc[1]);
  }
  VW0;
  #pragma unroll
  for (int q = 8; q < 16; ++q) {
    const int so = ((q*4 + kg) ^ swz) * 16;
    const bf8 a_h = asbf8(vh[q]), a_l = asbf8(vl[q]);
    const bf8 w0h = *(const bf8*)(Wh + r15*1024 + so);
    const bf8 w1h = *(const bf8*)(Wh + (16 + r15)*1024 + so);
    const bf8 w0l = *(const bf8*)(Wl + r15*1024 + so);
    const bf8 w1l = *(const bf8*)(Wl + (16 + r15)*1024 + so);
    MF(a_h, w0h, acc[0]); MF(a_l, w0h, acc[0]); MF(a_h, w0l, acc[0]);
    MF(a_h, w1h, acc[1]); MF(a_l, w1h, acc[1]); MF(a_h, w1l, acc[1]);
  }
}

// ---- role B epilogue: gate exchange + c/h update; lanes r15<8 own outputs ----
__device__ __forceinline__ void stepB_fin(const KP& kp, int m0, int j0, int jg,
    f4* acc, const float* bias, float* cst, u4* Ho, u4* Lo, int doPred)
{
  const int tid = threadIdx.x, wv = tid >> 6, lane = tid & 63;
  const int r15 = lane & 15, kg = lane >> 4;
  float og0[4], og1[4];
  #pragma unroll
  for (int c = 0; c < 4; ++c) {
    og0[c] = __shfl_xor(acc[0][c], 8, 64);
    og1[c] = __shfl_xor(acc[1][c], 8, 64);
  }
  const bool own = (r15 < 8);
  const int j = j0 + (r15 & 7);
  const float bi = bias[j], bfv = bias[Hh+j], bgv = bias[2*Hh+j], bo = bias[3*Hh+j];
  float hs[4];
  #pragma unroll
  for (int r = 0; r < 4; ++r) {
    const int bl = wv*16 + kg*4 + r;
    const size_t idx = (size_t)(m0 + bl)*Hh + j;
    const float gi = acc[0][r] + bi;     // gate i (own lanes)
    const float gf = og0[r]    + bfv;    // gate f (from partner)
    const float gg = acc[1][r] + bgv;    // gate g
    const float go = og1[r]    + bo;     // gate o
    const float cold = own ? cst[idx] : 0.f;
    const float c2 = sigm(gf) * cold + sigm(gi) * tanh_f(gg);
    const float h2 = sigm(go) * tanh_f(c2);
    if (own) cst[idx] = c2;
    const unsigned short hh2 = f2bf(h2);
    const unsigned short ll2 = f2bf(h2 - bf2f(hh2));
    const u4 ph = pack8(hh2, lane);
    const u4 pl = pack8(ll2, lane);
    const int slot = jg*256 + (m0 + wv*16 + kg*4 + r);
    if (r15 == 0) { st16(Ho + slot, ph); st16(Lo + slot, pl); }
    hs[r] = h2;
  }
  if (doPred) {
    const float lw = kp.linW[j];
    #pragma unroll
    for (int r = 0; r < 4; ++r) {
      float p = hs[r] * lw;
      p += __shfl_xor(p, 1, 64);
      p += __shfl_xor(p, 2, 64);
      p += __shfl_xor(p, 4, 64);
      if (r15 == 0)
        AST(&kp.pred[jg*Bb + (m0 + wv*16 + kg*4 + r)], p);
    }
  }
}

#define PH0(p) ((p) ? kp.h0h1 : kp.h0h0)
#define PL0(p) ((p) ? kp.h0l1 : kp.h0l0)
#define PH1(p) ((p) ? kp.h1h1 : kp.h1h0)
#define PL1(p) ((p) ? kp.h1l1 : kp.h1l0)

__global__ __launch_bounds__(512) void lstm_persist(KP kp) {
  extern __shared__ char L[];
  float* sS = (float*)(L + 131072);
  const int blk = blockIdx.x;
  const bool roleA = blk < 128;
  int m0, j0, jg;
  if (roleA) { jg = blk >> 2; m0 = (blk & 3) * 64; j0 = jg * 16; }
  else { const int b2 = blk - 128; jg = b2 >> 1; m0 = (b2 & 1) * 128; j0 = jg * 8; }

  if (roleA) stageA_w(kp.eWhh0h, kp.eWhh0l, j0, L);
  else { stageB_w(kp.eWih1h, kp.eWih1l, j0, L); stageB_w(kp.eWhh1h, kp.eWhh1l, j0, L + 65536); }

  unsigned rnd = 0;

  // ---- encoder: stage s = L0(t=s) || L1(t=s-1) ----
  for (int s = 0; s <= Tt; ++s) {
    if (roleA) {
      if (s < Tt)
        stepA(kp, L, sS, m0, j0, jg, PH0(s&1), PL0(s&1), kp.eWih0, kp.eb0,
              kp.c0, PH0((s+1)&1), PL0((s+1)&1), 0, s);
    } else {
      if (s >= 1) {
        f4 acc[2]; acc[0] = acc[1] = (f4){0.f,0.f,0.f,0.f};
        stepB_gemm(L,         PH0(s&1),     PL0(s&1),     m0, acc);  // h0(s) @ Wih1
        stepB_gemm(L + 65536, PH1((s-1)&1), PL1((s-1)&1), m0, acc);  // h1(s-1) @ Whh1
        stepB_fin(kp, m0, j0, jg, acc, kp.eb1, kp.c1, PH1(s&1), PL1(s&1), 0);
      }
    }
    gsync(kp.bar, rnd++);
  }

  // ---- transition: restage decoder weights ----
  if (roleA) stageA_w(kp.dWhh0h, kp.dWhh0l, j0, L);
  else { stageB_w(kp.dWih1h, kp.dWih1l, j0, L); stageB_w(kp.dWhh1h, kp.dWhh1l, j0, L + 65536); }

  // ---- decoder: 128 steps; role-B precomputes h1@Whh1 during cell0 phase ----
  for (int i = 0; i < NPR; ++i) {
    f4 acc[2]; acc[0] = acc[1] = (f4){0.f,0.f,0.f,0.f};
    if (roleA) {
      if (i == 0)
        stepA(kp, L, sS, m0, j0, jg, PH0(0), PL0(0), kp.dWih0, kp.db0,
              kp.c0, PH0(1), PL0(1), 0, Tt - 1);
      else
        stepA(kp, L, sS, m0, j0, jg, PH0(i&1), PL0(i&1), kp.dWih0, kp.db0,
              kp.c0, PH0((i+1)&1), PL0((i+1)&1), 1, i);
    } else {
      stepB_gemm(L + 65536, PH1(i&1), PL1(i&1), m0, acc);            // h1(i) @ Whh1 (pre)
    }
    gsync(kp.bar, rnd++);
    if (!roleA) {
      stepB_gemm(L, PH0((i+1)&1), PL0((i+1)&1), m0, acc);            // h0(i+1) @ Wih1
      stepB_fin(kp, m0, j0, jg, acc, kp.db1, kp.c1, PH1((i+1)&1), PL1((i+1)&1), 1);
    }
    gsync(kp.bar, rnd++);
  }

  // ---- tail: out[:,127] ----
  if (roleA && jg == 0 && threadIdx.x < 256) {
    const int tid = threadIdx.x, bl = tid >> 2, part = tid & 3, b = m0 + bl;
    float a = 0.f;
    #pragma unroll
    for (int u = 0; u < 16; ++u) a += ALD(&kp.pred[(part*16 + u)*Bb + b]);
    a += __shfl_xor(a, 1, 64);
    a += __shfl_xor(a, 2, 64);
    if (part == 0) kp.out[(size_t)b*NPR + 127] = a + kp.linb[0];
  }
}

__global__ __launch_bounds__(256) void conv_w(const float* __restrict__ src,
                                              unsigned short* __restrict__ hi,
                                              unsigned short* __restrict__ lo) {
  const int i = (blockIdx.x * 256 + threadIdx.x) * 4;
  const float4 v = *(const float4*)(src + i);
  const unsigned short h0 = f2bf(v.x), h1 = f2bf(v.y), h2 = f2bf(v.z), h3 = f2bf(v.w);
  ushort4 hv; hv.x = h0; hv.y = h1; hv.z = h2; hv.w = h3;
  ushort4 lv;
  lv.x = f2bf(v.x - bf2f(h0)); lv.y = f2bf(v.y - bf2f(h1));
  lv.z = f2bf(v.z - bf2f(h2)); lv.w = f2bf(v.w - bf2f(h3));
  *(ushort4*)(hi + i) = hv;
  *(ushort4*)(lo + i) = lv;
}

extern "C" void kernel_launch(void* const* d_in, const int* in_sizes, int n_in,
                              void* d_out, int out_size, void* d_ws, size_t ws_size,
                              hipStream_t stream) {
  const float* x     = (const float*)d_in[0];
  const float* eWih0 = (const float*)d_in[1];
  const float* eWhh0 = (const float*)d_in[2];
  const float* eb0   = (const float*)d_in[3];
  const float* eWih1 = (const float*)d_in[4];
  const float* eWhh1 = (const float*)d_in[5];
  const float* eb1   = (const float*)d_in[6];
  const float* dWih0 = (const float*)d_in[7];
  const float* dWhh0 = (const float*)d_in[8];
  const float* db0   = (const float*)d_in[9];
  const float* dWih1 = (const float*)d_in[10];
  const float* dWhh1 = (const float*)d_in[11];
  const float* db1   = (const float*)d_in[12];
  const float* linW  = (const float*)d_in[13];
  const float* linb  = (const float*)d_in[14];
  float* out = (float*)d_out;

  unsigned short* wb = (unsigned short*)d_ws;
  unsigned short* W[12];
  for (int k = 0; k < 12; ++k) W[k] = wb + (size_t)k*WN;
  unsigned short* sb = wb + (size_t)12*WN;   // 8 h buffers (hT layout)
  float* cb   = (float*)(sb + (size_t)8*BH);
  float* c0   = cb;
  float* c1   = cb + BH;
  float* pred = cb + 2*(size_t)BH;           // 64*256 floats
  unsigned* bar = (unsigned*)(pred + 64*Bb);

  (void)hipMemsetAsync(sb + 0*(size_t)BH, 0, (size_t)BH*2, stream); // h0h[0]
  (void)hipMemsetAsync(sb + 2*(size_t)BH, 0, (size_t)BH*2, stream); // h0l[0]
  (void)hipMemsetAsync(sb + 4*(size_t)BH, 0, (size_t)BH*2, stream); // h1h[0]
  (void)hipMemsetAsync(sb + 6*(size_t)BH, 0, (size_t)BH*2, stream); // h1l[0]
  (void)hipMemsetAsync(c0, 0, (size_t)BH*4, stream);
  (void)hipMemsetAsync(c1, 0, (size_t)BH*4, stream);
  (void)hipMemsetAsync(bar, 0, 4096, stream);

  conv_w<<<1024, 256, 0, stream>>>(eWhh0, W[0], W[1]);
  conv_w<<<1024, 256, 0, stream>>>(eWih1, W[2], W[3]);
  conv_w<<<1024, 256, 0, stream>>>(eWhh1, W[4], W[5]);
  conv_w<<<1024, 256, 0, stream>>>(dWhh0, W[6], W[7]);
  conv_w<<<1024, 256, 0, stream>>>(dWih1, W[8], W[9]);
  conv_w<<<1024, 256, 0, stream>>>(dWhh1, W[10], W[11]);

  KP kp;
  kp.x = x; kp.eb0 = eb0; kp.eb1 = eb1; kp.db0 = db0; kp.db1 = db1;
  kp.eWih0 = eWih0; kp.dWih0 = dWih0; kp.linW = linW; kp.linb = linb;
  kp.eWhh0h = W[0]; kp.eWhh0l = W[1];
  kp.eWih1h = W[2]; kp.eWih1l = W[3];
  kp.eWhh1h = W[4]; kp.eWhh1l = W[5];
  kp.dWhh0h = W[6]; kp.dWhh0l = W[7];
  kp.dWih1h = W[8]; kp.dWih1l = W[9];
  kp.dWhh1h = W[10]; kp.dWhh1l = W[11];
  kp.h0h0 = (u4*)(sb + 0*(size_t)BH); kp.h0h1 = (u4*)(sb + 1*(size_t)BH);
  kp.h0l0 = (u4*)(sb + 2*(size_t)BH); kp.h0l1 = (u4*)(sb + 3*(size_t)BH);
  kp.h1h0 = (u4*)(sb + 4*(size_t)BH); kp.h1h1 = (u4*)(sb + 5*(size_t)BH);
  kp.h1l0 = (u4*)(sb + 6*(size_t)BH); kp.h1l1 = (u4*)(sb + 7*(size_t)BH);
  kp.c0 = c0; kp.c1 = c1; kp.pred = pred; kp.out = out; kp.bar = bar;

  (void)hipFuncSetAttribute((const void*)lstm_persist,
                            hipFuncAttributeMaxDynamicSharedMemorySize, LDSB);
  void* kargs[] = { (void*)&kp };
  hipError_t rc = hipLaunchCooperativeKernel((const void*)lstm_persist, dim3(256), dim3(512),
                                             kargs, LDSB, stream);
  if (rc != hipSuccess) {
    lstm_persist<<<dim3(256), dim3(512), LDSB, stream>>>(kp);
  }
  (void)in_sizes; (void)n_in; (void)out_size; (void)ws_size;
}